// Round 10
// baseline (1163.210 us; speedup 1.0000x reference)
//
#include <hip/hip_runtime.h>
#include <hip/hip_bf16.h>
#include <hip/hip_cooperative_groups.h>
namespace cg = cooperative_groups;

#define BB 16
#define NN 1024
#define FF 128
#define HH 192
#define NROWS (BB*NN)
#define MAXC 128
#define EPSV 1e-5f
#define NBLK 256
#define SMEM_BYTES (NN*12*4)     // 48 KB: spmm staging; reused by other phases

// workspace layout, in float (4B) units (~17 MB total)
constexpr size_t OFF_H0  = 0;                                   // [NROWS*HH] bf16
constexpr size_t OFF_ZB  = OFF_H0 + (size_t)NROWS*HH/2;         // [NROWS*HH] bf16
constexpr size_t OFF_WPF = OFF_ZB + (size_t)NROWS*HH/2;         // [HH*FF] bf16 feat W'T
constexpr size_t OFF_WPC = OFF_WPF + (size_t)HH*FF/2;           // [HH*HH] bf16 conv W'T
constexpr size_t OFF_BF  = OFF_WPC + (size_t)HH*HH/2;           // [HH] f32
constexpr size_t OFF_BC  = OFF_BF + HH;                         // [HH] f32
constexpr size_t OFF_DIS = OFF_BC + HH;                         // [NROWS] f32
constexpr size_t OFF_G   = OFF_DIS + NROWS;                     // [BB*HH] f32 pool (atomics)
constexpr size_t OFF_ST  = OFF_G + BB*HH;                       // 4 stages x 8 buckets x 512
constexpr size_t ST_SIZE = 4*8*512;
constexpr size_t OFF_FLAG= OFF_ST + ST_SIZE;                    // 1 int
constexpr size_t OFF_CNT = OFF_FLAG + 1;                        // [NROWS] i32
constexpr size_t OFF_COLS= OFF_CNT + NROWS;                     // [NROWS*MAXC] u16

typedef __attribute__((ext_vector_type(8))) short short8;
typedef __attribute__((ext_vector_type(4))) float f32x4;
typedef __attribute__((ext_vector_type(4))) unsigned int u32x4;
typedef __attribute__((ext_vector_type(2))) unsigned int u32x2;

static __device__ __forceinline__ float bf(const __hip_bfloat16 v) {
    return __bfloat162float(v);
}
static __device__ __forceinline__ float ldin(const void* p, size_t i, int isf) {
    return isf ? ((const float*)p)[i]
               : __bfloat162float(((const __hip_bfloat16*)p)[i]);
}
static __host__ __device__ __forceinline__ float* stage_hh(float* ws, int s /*0..2*/) {
    return ws + OFF_ST + (size_t)8*512*(1 + s);     // s index: feat-out = 0
}
static __device__ __forceinline__ float blo(unsigned int u) {
    union { unsigned int x; float f; } v; v.x = u << 16; return v.f;
}
static __device__ __forceinline__ float bhi(unsigned int u) {
    union { unsigned int x; float f; } v; v.x = u & 0xFFFF0000u; return v.f;
}
static __device__ __forceinline__ unsigned int packbf(float a, float b) {
    union { unsigned int u; __hip_bfloat16 h[2]; } p;
    p.h[0] = __float2bfloat16(a); p.h[1] = __float2bfloat16(b);
    return p.u;
}

// ---------- device bodies (shared by cooperative mega and fallback kernels) ----------

// block 0: dtype-detect into ws[OFF_FLAG]; all blocks: zero pool+stat accumulators
static __device__ void init_body(const unsigned int* __restrict__ adjw, float* ws,
                                 int bi, int tid, int* evid) {
    if (bi == 0) {
        if (tid == 0) *evid = 0;
        __syncthreads();
        int local = 0;
        for (int k = tid; k < 16384; k += 256)
            if ((adjw[k] & 0xFFFFu) == 0x3F80u) local++;   // bf16-packed even-idx 1.0
        if (local) atomicAdd(evid, local);
        __syncthreads();
        if (tid == 0) ((int*)ws)[OFF_FLAG] = (*evid == 0) ? 1 : 0;
    }
    size_t ztot = BB*HH + ST_SIZE;          // OFF_G..OFF_FLAG contiguous
    for (size_t i = (size_t)bi*256 + tid; i < ztot; i += (size_t)NBLK*256)
        ws[OFF_G + i] = 0.f;
}

// graph build (64 rows/block; 4 rows x 64 lanes) + x-stats over same 64 rows
static __device__ void graph_body(const void* __restrict__ adj,
                                  const void* __restrict__ x, float* ws,
                                  int isf, int bi, int tid, unsigned char* smem) {
    int* cnt_s = (int*)smem;                                  // [4]
    unsigned short* colbuf = (unsigned short*)(smem + 16);    // [4][MAXC]
    int* cntg = (int*)(ws + OFF_CNT);
    unsigned short* colsg = (unsigned short*)(ws + OFF_COLS);
    int r4 = tid >> 6, tl = tid & 63;
    for (int rr = 0; rr < 16; ++rr) {
        int row = bi*64 + rr*4 + r4;
        int i = row & (NN - 1);
        if (tl == 0) cnt_s[r4] = 0;
        __syncthreads();
        #pragma unroll
        for (int p = 0; p < 4; ++p) {
            int j0 = p*256 + tl*4;
            unsigned int bits[4];
            if (isf) {
                u32x4 v = *(const u32x4*)((const unsigned int*)adj + (size_t)row*NN + j0);
                bits[0]=v[0]; bits[1]=v[1]; bits[2]=v[2]; bits[3]=v[3];
            } else {
                u32x2 v = *(const u32x2*)((const unsigned short*)adj + (size_t)row*NN + j0);
                bits[0]=(v[0]&0xFFFFu); bits[1]=(v[0]>>16);
                bits[2]=(v[1]&0xFFFFu); bits[3]=(v[1]>>16);
            }
            #pragma unroll
            for (int e = 0; e < 4; ++e) {
                int j = j0 + e;
                if ((bits[e] << 1) != 0u || j == i) {
                    int p2 = atomicAdd(&cnt_s[r4], 1);
                    if (p2 < MAXC) colbuf[r4*MAXC + p2] = (unsigned short)j;
                }
            }
        }
        __syncthreads();
        int c = cnt_s[r4]; if (c > MAXC) c = MAXC;
        if (tl == 0) {
            cntg[row] = c;
            ws[OFF_DIS + row] = rsqrtf((float)cnt_s[r4]);
        }
        for (int k = tl; k < c; k += 64) colsg[(size_t)row*MAXC + k] = colbuf[r4*MAXC + k];
        __syncthreads();
    }
    // x-stats over rows bi*64..bi*64+63
    float* xs = (float*)smem;
    int f = tid & 127, rr2 = tid >> 7;
    float s = 0.f, q = 0.f;
    int r0 = bi*64;
    for (int r = rr2; r < 64; r += 2) {
        float v = ldin(x, (size_t)(r0 + r)*FF + f, isf);
        s += v; q += v*v;
    }
    __syncthreads();
    if (rr2 == 1) { xs[f] = s; xs[128 + f] = q; }
    __syncthreads();
    if (rr2 == 0) {
        s += xs[f]; q += xs[128 + f];
        float* st = ws + OFF_ST + (size_t)(bi & 7)*512;
        atomicAdd(&st[f], s);
        atomicAdd(&st[256 + f], q);
    }
    __syncthreads();
}

// BN-fold feat: W'T[n][k] = a_k W[k][n]; biasF[n] = sum_k c_k W[k][n]. n = block.
static __device__ void prep_feat_body(const void* __restrict__ W_feat,
                                      const void* __restrict__ gg, const void* __restrict__ bb,
                                      float* ws, int isf, int n, int tid, float* red) {
    int k = tid;
    if (k < FF) {
        const float* st = ws + OFF_ST;
        float s = 0.f, q = 0.f;
        #pragma unroll
        for (int b = 0; b < 8; ++b) { s += st[b*512 + k]; q += st[b*512 + 256 + k]; }
        float mm = s * (1.f/NROWS);
        float var = q * (1.f/NROWS) - mm*mm;
        float a = ldin(gg, k, isf) * rsqrtf(var + EPSV);
        float cc = ldin(bb, k, isf) - mm*a;
        float wv = ldin(W_feat, (size_t)k*HH + n, isf);
        ((__hip_bfloat16*)(ws + OFF_WPF))[(size_t)n*FF + k] = __float2bfloat16(a*wv);
        red[k] = cc*wv;
    }
    __syncthreads();
    for (int s2 = 64; s2 > 0; s2 >>= 1) {
        if (tid < s2 && tid + s2 < FF) red[tid] += red[tid + s2];
        __syncthreads();
    }
    if (tid == 0) ws[OFF_BF + n] = red[0];
    __syncthreads();
}

static __device__ void prep_conv_body(const void* __restrict__ convs_W,
                                      const void* __restrict__ gg, const void* __restrict__ bb,
                                      int l, float* ws, int isf, int n, int tid, float* red) {
    int k = tid;
    if (k < HH) {
        const float* st = stage_hh(ws, l);
        float s = 0.f, q = 0.f;
        #pragma unroll
        for (int b = 0; b < 8; ++b) { s += st[b*512 + k]; q += st[b*512 + 256 + k]; }
        float mm = s * (1.f/NROWS);
        float var = q * (1.f/NROWS) - mm*mm;
        float a = ldin(gg, (size_t)l*HH + k, isf) * rsqrtf(var + EPSV);
        float cc = ldin(bb, (size_t)l*HH + k, isf) - mm*a;
        float wv = ldin(convs_W, (size_t)l*HH*HH + (size_t)k*HH + n, isf);
        ((__hip_bfloat16*)(ws + OFF_WPC))[(size_t)n*HH + k] = __float2bfloat16(a*wv);
        red[k] = cc*wv;
    }
    __syncthreads();
    if (tid < 96) red[tid] += red[tid + 96];
    __syncthreads();
    for (int s2 = 48; s2 >= 3; s2 >>= 1) {
        if (tid < s2) red[tid] += red[tid + s2];
        __syncthreads();
    }
    if (tid == 0) ws[OFF_BC + n] = red[0] + red[1] + red[2];
    __syncthreads();
}

// MFMA GEMM, 32 rows x 192 cols per call (half = 0/1 selects 32-row half of the
// block's 64 rows). mode 0: A=x, H0=bf16(relu(C)), stats. mode 1: A=H0, Z'=dis*C.
static __device__ void gemm_body(int K, int mode, const void* __restrict__ A,
                                 const __hip_bfloat16* __restrict__ BT,
                                 const float* __restrict__ bias,
                                 int isf, int bi, int half, int tid,
                                 float* __restrict__ ws, unsigned char* smem) {
    int lane = tid & 63, w = tid >> 6;
    int wr = w & 1, wc = w >> 1;
    int batch = bi & 15, seg = bi >> 4;               // seg 0..15
    int row0 = batch*NN + seg*64 + half*32 + wr*16;
    int col0 = wc*96;
    int m = lane & 15, quad = lane >> 4;
    f32x4 acc[6];
    #pragma unroll
    for (int t = 0; t < 6; ++t) acc[t] = f32x4{0.f,0.f,0.f,0.f};
    float bv[6];
    #pragma unroll
    for (int t = 0; t < 6; ++t) bv[t] = bias[col0 + t*16 + m];
    for (int kb = 0; kb < K/32; ++kb) {
        short8 a;
        if (mode == 0 && isf) {
            const float* Ar = (const float*)A + (size_t)(row0+m)*K + kb*32 + quad*8;
            f32x4 v0 = *(const f32x4*)Ar;
            f32x4 v1 = *(const f32x4*)(Ar + 4);
            union { short8 s8; __hip_bfloat16 h[8]; } u;
            #pragma unroll
            for (int e = 0; e < 4; ++e) {
                u.h[e]   = __float2bfloat16(v0[e]);
                u.h[e+4] = __float2bfloat16(v1[e]);
            }
            a = u.s8;
        } else {
            a = *(const short8*)((const __hip_bfloat16*)A +
                                 (size_t)(row0+m)*K + kb*32 + quad*8);
        }
        #pragma unroll
        for (int t = 0; t < 6; ++t) {
            short8 b = *(const short8*)(BT + (size_t)(col0 + t*16+m)*K + kb*32 + quad*8);
            acc[t] = __builtin_amdgcn_mfma_f32_16x16x32_bf16(a, b, acc[t], 0, 0, 0);
        }
    }
    if (mode == 0) {
        float* sh = (float*)smem;                  // [2*HH]
        for (int i = tid; i < 2*HH; i += 256) sh[i] = 0.f;
        __syncthreads();
        __hip_bfloat16* H0 = (__hip_bfloat16*)(ws + OFF_H0);
        #pragma unroll
        for (int t = 0; t < 6; ++t) {
            int ch = col0 + t*16 + m;
            float s = 0.f, sq = 0.f;
            #pragma unroll
            for (int r = 0; r < 4; ++r) {
                float o = fmaxf(acc[t][r] + bv[t], 0.f);
                H0[(size_t)(row0 + quad*4 + r)*HH + ch] = __float2bfloat16(o);
                s += o; sq += o*o;
            }
            atomicAdd(&sh[ch], s);
            atomicAdd(&sh[HH + ch], sq);
        }
        __syncthreads();
        float* st = stage_hh(ws, 0) + (size_t)(bi & 7)*512;
        if (tid < HH) {
            atomicAdd(&st[tid], sh[tid]);
            atomicAdd(&st[256 + tid], sh[HH + tid]);
        }
        __syncthreads();
    } else {
        const float* dis = ws + OFF_DIS;
        __hip_bfloat16* Z = (__hip_bfloat16*)(ws + OFF_ZB);
        float sc[4];
        #pragma unroll
        for (int r = 0; r < 4; ++r) sc[r] = dis[row0 + quad*4 + r];
        #pragma unroll
        for (int t = 0; t < 6; ++t)
            #pragma unroll
            for (int r = 0; r < 4; ++r)
                Z[(size_t)(row0 + quad*4 + r)*HH + col0 + t*16 + m] =
                    __float2bfloat16((acc[t][r] + bv[t]) * sc[r]);
    }
}

// LDS-staged SpMM: 24-ch slice (48 KB). 256 blocks = batch(16) x slice(8) x rgrp(2).
// 256 thr = 64 rslots x 4 d (6 ch each); 8 row-iterations (512 rows per rgrp).
static __device__ void spmm_body(int l, const void* __restrict__ convs_b,
                                 int isf, int bi, int tid,
                                 float* __restrict__ ws, unsigned char* smem) {
    unsigned int* Zs = (unsigned int*)smem;       // [NN*12]
    int batch = bi & 15;
    int rest  = bi >> 4;                          // 0..15
    int slice = rest & 7;
    int rgrp  = rest >> 3;                        // 0..1
    int c0 = slice*24;
    const unsigned int* Zu = (const unsigned int*)(ws + OFF_ZB)
                             + (size_t)batch*NN*96 + slice*12;
    for (int i = tid; i < NN*12; i += 256) {
        int r = i / 12, u = i - r*12;
        Zs[i] = Zu[(size_t)r*96 + u];
    }
    __syncthreads();
    int d = tid & 3, rslot = tid >> 2;
    const float* dis = ws + OFF_DIS;
    const int* cnt = (const int*)(ws + OFF_CNT);
    const unsigned short* cols = (const unsigned short*)(ws + OFF_COLS);
    unsigned int* H0u = (unsigned int*)(ws + OFF_H0);
    float bch[6];
    #pragma unroll
    for (int e = 0; e < 6; ++e)
        bch[e] = ldin(convs_b, (size_t)l*HH + c0 + d*6 + e, isf);
    float s_acc[6] = {0,0,0,0,0,0}, q_acc[6] = {0,0,0,0,0,0};
    for (int it = 0; it < 8; ++it) {
        int row = batch*NN + rgrp*512 + it*64 + rslot;
        int c = cnt[row];
        const unsigned short* cl = cols + (size_t)row*MAXC;
        float a[6] = {0,0,0,0,0,0};
        int k = 0;
        for (; k + 4 <= c; k += 4) {
            u32x2 cw = *(const u32x2*)(cl + k);
            int j0=(int)(cw[0]&0xFFFFu), j1=(int)(cw[0]>>16);
            int j2=(int)(cw[1]&0xFFFFu), j3=(int)(cw[1]>>16);
            int o0=j0*12+d*3, o1=j1*12+d*3, o2=j2*12+d*3, o3=j3*12+d*3;
            unsigned int z[12];
            z[0]=Zs[o0]; z[1]=Zs[o0+1]; z[2]=Zs[o0+2];
            z[3]=Zs[o1]; z[4]=Zs[o1+1]; z[5]=Zs[o1+2];
            z[6]=Zs[o2]; z[7]=Zs[o2+1]; z[8]=Zs[o2+2];
            z[9]=Zs[o3]; z[10]=Zs[o3+1]; z[11]=Zs[o3+2];
            #pragma unroll
            for (int g = 0; g < 4; ++g) {
                a[0]+=blo(z[g*3]);   a[1]+=bhi(z[g*3]);
                a[2]+=blo(z[g*3+1]); a[3]+=bhi(z[g*3+1]);
                a[4]+=blo(z[g*3+2]); a[5]+=bhi(z[g*3+2]);
            }
        }
        for (; k < c; ++k) {
            int o = (int)cl[k]*12 + d*3;
            unsigned int z0=Zs[o], z1=Zs[o+1], z2=Zs[o+2];
            a[0]+=blo(z0); a[1]+=bhi(z0);
            a[2]+=blo(z1); a[3]+=bhi(z1);
            a[4]+=blo(z2); a[5]+=bhi(z2);
        }
        float dd = dis[row];
        float o0 = fmaxf(dd*a[0] + bch[0], 0.f);
        float o1 = fmaxf(dd*a[1] + bch[1], 0.f);
        float o2 = fmaxf(dd*a[2] + bch[2], 0.f);
        float o3 = fmaxf(dd*a[3] + bch[3], 0.f);
        float o4 = fmaxf(dd*a[4] + bch[4], 0.f);
        float o5 = fmaxf(dd*a[5] + bch[5], 0.f);
        size_t hb = (size_t)row*96 + slice*12 + d*3;
        H0u[hb]   = packbf(o0,o1);
        H0u[hb+1] = packbf(o2,o3);
        H0u[hb+2] = packbf(o4,o5);
        s_acc[0]+=o0; s_acc[1]+=o1; s_acc[2]+=o2; s_acc[3]+=o3; s_acc[4]+=o4; s_acc[5]+=o5;
        q_acc[0]+=o0*o0; q_acc[1]+=o1*o1; q_acc[2]+=o2*o2;
        q_acc[3]+=o3*o3; q_acc[4]+=o4*o4; q_acc[5]+=o5*o5;
    }
    #pragma unroll
    for (int e = 0; e < 6; ++e) {
        #pragma unroll
        for (int mask = 4; mask < 64; mask <<= 1) {
            s_acc[e] += __shfl_xor(s_acc[e], mask, 64);
            q_acc[e] += __shfl_xor(q_acc[e], mask, 64);
        }
    }
    if ((tid & 63) < 4) {
        if (l == 2) {
            #pragma unroll
            for (int e = 0; e < 6; ++e)
                atomicAdd(&ws[OFF_G + (size_t)batch*HH + c0 + d*6 + e], s_acc[e]);
        } else {
            float* st = stage_hh(ws, l + 1) + (size_t)(bi & 7)*512;
            #pragma unroll
            for (int e = 0; e < 6; ++e) {
                atomicAdd(&st[c0 + d*6 + e],       s_acc[e]);
                atomicAdd(&st[256 + c0 + d*6 + e], q_acc[e]);
            }
        }
    }
    __syncthreads();
}

// ---------------- cooperative mega kernel (256 blocks x 256 thr) ----------------
__global__ __launch_bounds__(256) void mega(const void* __restrict__ x,
        const void* __restrict__ adj,
        const void* __restrict__ bnf_g, const void* __restrict__ bnf_b,
        const void* __restrict__ W_feat,
        const void* __restrict__ bnc_g, const void* __restrict__ bnc_b,
        const void* __restrict__ convs_W, const void* __restrict__ convs_b,
        float* __restrict__ ws) {
    cg::grid_group grid = cg::this_grid();
    __shared__ __align__(16) unsigned char smem[SMEM_BYTES];
    int tid = threadIdx.x, bi = blockIdx.x;

    init_body((const unsigned int*)adj, ws, bi, tid, (int*)smem);
    __threadfence(); grid.sync(); __threadfence();

    const int isf = ((const int*)ws)[OFF_FLAG];

    graph_body(adj, x, ws, isf, bi, tid, smem);
    __threadfence(); grid.sync(); __threadfence();

    if (bi < HH) prep_feat_body(W_feat, bnf_g, bnf_b, ws, isf, bi, tid, (float*)smem);
    __threadfence(); grid.sync(); __threadfence();

    for (int half = 0; half < 2; ++half)
        gemm_body(FF, 0, x, (const __hip_bfloat16*)(ws + OFF_WPF), ws + OFF_BF,
                  isf, bi, half, tid, ws, smem);
    __threadfence(); grid.sync(); __threadfence();

    for (int l = 0; l < 3; ++l) {
        if (bi < HH) prep_conv_body(convs_W, bnc_g, bnc_b, l, ws, isf, bi, tid, (float*)smem);
        __threadfence(); grid.sync(); __threadfence();

        for (int half = 0; half < 2; ++half)
            gemm_body(HH, 1, (const void*)(ws + OFF_H0),
                      (const __hip_bfloat16*)(ws + OFF_WPC), ws + OFF_BC,
                      isf, bi, half, tid, ws, smem);
        __threadfence(); grid.sync(); __threadfence();

        spmm_body(l, convs_b, isf, bi, tid, ws, smem);
        if (l < 2) { __threadfence(); grid.sync(); __threadfence(); }
    }
}

// ---------------- fallback discrete kernels (same bodies) ----------------
__global__ __launch_bounds__(256) void k_init(const unsigned int* __restrict__ adjw,
                                              float* ws) {
    __shared__ int evid;
    init_body(adjw, ws, blockIdx.x, threadIdx.x, &evid);
}
__global__ __launch_bounds__(256) void k_graph(const void* __restrict__ adj,
                                               const void* __restrict__ x, float* ws) {
    __shared__ __align__(16) unsigned char sm[2048];
    const int isf = ((const int*)ws)[OFF_FLAG];
    graph_body(adj, x, ws, isf, blockIdx.x, threadIdx.x, sm);
}
__global__ __launch_bounds__(256) void k_prep_feat(const void* __restrict__ W_feat,
        const void* __restrict__ gg, const void* __restrict__ bb, float* ws) {
    __shared__ float red[FF];
    const int isf = ((const int*)ws)[OFF_FLAG];
    prep_feat_body(W_feat, gg, bb, ws, isf, blockIdx.x, threadIdx.x, red);
}
__global__ __launch_bounds__(256) void k_prep_conv(const void* __restrict__ convs_W,
        const void* __restrict__ gg, const void* __restrict__ bb, int l, float* ws) {
    __shared__ float red[HH];
    const int isf = ((const int*)ws)[OFF_FLAG];
    prep_conv_body(convs_W, gg, bb, l, ws, isf, blockIdx.x, threadIdx.x, red);
}
__global__ __launch_bounds__(256) void k_gemm_feat(const void* __restrict__ x, float* ws) {
    __shared__ __align__(16) unsigned char sm[2*HH*4];
    const int isf = ((const int*)ws)[OFF_FLAG];
    for (int half = 0; half < 2; ++half)
        gemm_body(FF, 0, x, (const __hip_bfloat16*)(ws + OFF_WPF), ws + OFF_BF,
                  isf, blockIdx.x, half, threadIdx.x, ws, sm);
}
__global__ __launch_bounds__(256) void k_gemm_conv(int l, float* ws) {
    const int isf = ((const int*)ws)[OFF_FLAG];
    for (int half = 0; half < 2; ++half)
        gemm_body(HH, 1, (const void*)(ws + OFF_H0),
                  (const __hip_bfloat16*)(ws + OFF_WPC), ws + OFF_BC,
                  isf, blockIdx.x, half, threadIdx.x, ws, nullptr);
    (void)l;
}
__global__ __launch_bounds__(256) void k_spmm(const void* __restrict__ convs_b,
                                              int l, float* ws) {
    __shared__ __align__(16) unsigned char sm[SMEM_BYTES];
    const int isf = ((const int*)ws)[OFF_FLAG];
    spmm_body(l, convs_b, isf, blockIdx.x, threadIdx.x, ws, sm);
}

// BN -> relu(linear) -> BN -> classifier -> log_softmax. One block, 768 thr.
__global__ __launch_bounds__(768) void tail(
                     const void* __restrict__ fc_g,  const void* __restrict__ fc_b,
                     const void* __restrict__ lin_W, const void* __restrict__ lin_b,
                     const void* __restrict__ hid_g, const void* __restrict__ hid_b,
                     const void* __restrict__ cls_W, const void* __restrict__ cls_b,
                     void* __restrict__ out, const float* ws) {
    __shared__ float g1[BB][HH];
    __shared__ float g2[BB][HH];
    __shared__ __hip_bfloat16 Wl[HH*HH];
    __shared__ float logits[BB][10];
    __shared__ float lse[BB];
    int tid = threadIdx.x;
    const int isf = ((const int*)ws)[OFF_FLAG];
    const float* g = ws + OFF_G;   // sums over N; scale by 1/NN
    if (isf) {
        const float* Wp = (const float*)lin_W;
        for (int i = tid; i < HH*HH; i += 768) Wl[i] = __float2bfloat16(Wp[i]);
    } else {
        const __hip_bfloat16* Wp = (const __hip_bfloat16*)lin_W;
        for (int i = tid; i < HH*HH; i += 768) Wl[i] = Wp[i];
    }
    if (tid < HH) {
        float s = 0.f, sq = 0.f;
        for (int b = 0; b < BB; ++b) {
            float v = g[b*HH + tid] * (1.f/NN);
            s += v; sq += v*v;
        }
        float m = s*(1.f/BB), var = sq*(1.f/BB) - m*m;
        float a = ldin(fc_g, tid, isf) * rsqrtf(var + EPSV);
        float c = ldin(fc_b, tid, isf) - m*a;
        for (int b = 0; b < BB; ++b) g1[b][tid] = g[b*HH + tid]*(1.f/NN)*a + c;
    }
    __syncthreads();
    {
        int n = tid % HH, bg = tid / HH;
        float lb = ldin(lin_b, n, isf);
        float a0 = lb, a1 = lb, a2 = lb, a3 = lb;
        int b0 = bg*4;
        for (int k = 0; k < HH; ++k) {
            float wv = bf(Wl[k*HH + n]);
            a0 += g1[b0+0][k]*wv;
            a1 += g1[b0+1][k]*wv;
            a2 += g1[b0+2][k]*wv;
            a3 += g1[b0+3][k]*wv;
        }
        g2[b0+0][n] = fmaxf(a0, 0.f);
        g2[b0+1][n] = fmaxf(a1, 0.f);
        g2[b0+2][n] = fmaxf(a2, 0.f);
        g2[b0+3][n] = fmaxf(a3, 0.f);
    }
    __syncthreads();
    if (tid < HH) {
        float s = 0.f, sq = 0.f;
        for (int b = 0; b < BB; ++b) { float v = g2[b][tid]; s += v; sq += v*v; }
        float m = s*(1.f/BB), var = sq*(1.f/BB) - m*m;
        float a = ldin(hid_g, tid, isf) * rsqrtf(var + EPSV);
        float c = ldin(hid_b, tid, isf) - m*a;
        for (int b = 0; b < BB; ++b) g2[b][tid] = g2[b][tid]*a + c;
    }
    __syncthreads();
    if (tid < BB*10) {
        int b = tid/10, k = tid%10;
        float acc = ldin(cls_b, k, isf);
        for (int h = 0; h < HH; ++h) acc += g2[b][h] * ldin(cls_W, (size_t)h*10 + k, isf);
        logits[b][k] = acc;
    }
    __syncthreads();
    if (tid < BB) {
        float m = -1e30f;
        for (int k = 0; k < 10; ++k) m = fmaxf(m, logits[tid][k]);
        float s = 0.f;
        for (int k = 0; k < 10; ++k) s += expf(logits[tid][k] - m);
        lse[tid] = m + logf(s);
    }
    __syncthreads();
    if (tid < BB*10) {
        int b = tid/10;
        float v = logits[b][tid%10] - lse[b];
        if (isf) ((float*)out)[tid] = v;
        else     ((__hip_bfloat16*)out)[tid] = __float2bfloat16(v);
    }
}

extern "C" void kernel_launch(void* const* d_in, const int* in_sizes, int n_in,
                              void* d_out, int out_size, void* d_ws, size_t ws_size,
                              hipStream_t stream) {
    const void* x       = d_in[0];
    const void* adj     = d_in[1];
    const void* bnf_g   = d_in[2];
    const void* bnf_b   = d_in[3];
    const void* W_feat  = d_in[4];
    const void* bnc_g   = d_in[5];
    const void* bnc_b   = d_in[6];
    const void* convs_W = d_in[7];
    const void* convs_b = d_in[8];
    const void* fc_g    = d_in[9];
    const void* fc_b    = d_in[10];
    const void* lin_W   = d_in[11];
    const void* lin_b   = d_in[12];
    const void* hid_g   = d_in[13];
    const void* hid_b   = d_in[14];
    const void* cls_W   = d_in[15];
    const void* cls_b   = d_in[16];

    float* ws = (float*)d_ws;

    void* args[] = {(void*)&x, (void*)&adj, (void*)&bnf_g, (void*)&bnf_b,
                    (void*)&W_feat, (void*)&bnc_g, (void*)&bnc_b,
                    (void*)&convs_W, (void*)&convs_b, (void*)&ws};
    hipError_t cerr = hipLaunchCooperativeKernel(reinterpret_cast<void*>(mega),
                                                 dim3(NBLK), dim3(256), args, 0, stream);
    if (cerr != hipSuccess) {
        (void)hipGetLastError();   // clear sticky error; fall back to discrete kernels
        k_init<<<NBLK, 256, 0, stream>>>((const unsigned int*)adj, ws);
        k_graph<<<NBLK, 256, 0, stream>>>(adj, x, ws);
        k_prep_feat<<<HH, 256, 0, stream>>>(W_feat, bnf_g, bnf_b, ws);
        k_gemm_feat<<<NBLK, 256, 0, stream>>>(x, ws);
        for (int l = 0; l < 3; ++l) {
            k_prep_conv<<<HH, 256, 0, stream>>>(convs_W, bnc_g, bnc_b, l, ws);
            k_gemm_conv<<<NBLK, 256, 0, stream>>>(l, ws);
            k_spmm<<<NBLK, 256, 0, stream>>>(convs_b, l, ws);
        }
    }
    tail<<<1, 768, 0, stream>>>(fc_g, fc_b, lin_W, lin_b,
                                hid_g, hid_b, cls_W, cls_b, d_out, ws);
}

// Round 11
// 953.356 us; speedup vs baseline: 1.2201x; 1.2201x over previous
//
#include <hip/hip_runtime.h>
#include <hip/hip_bf16.h>

#define BB 16
#define NN 1024
#define FF 128
#define HH 192
#define NROWS (BB*NN)
#define MAXC 128
#define EPSV 1e-5f

// workspace layout, in float (4B) units (~17 MB total)
constexpr size_t OFF_H0  = 0;                                   // [NROWS*HH] bf16 (h, post-relu)
constexpr size_t OFF_ZB  = OFF_H0 + (size_t)NROWS*HH/2;         // [NROWS*HH] bf16 (Z' = dis_j*(hW'+bias))
constexpr size_t OFF_WPF = OFF_ZB + (size_t)NROWS*HH/2;         // [HH*FF] bf16  feat W'T
constexpr size_t OFF_WPC = OFF_WPF + (size_t)HH*FF/2;           // [HH*HH] bf16  conv W'T (per layer)
constexpr size_t OFF_BF  = OFF_WPC + (size_t)HH*HH/2;           // [HH] f32 feat bias (c@W)
constexpr size_t OFF_BC  = OFF_BF + HH;                         // [HH] f32 conv bias (c@W)
constexpr size_t OFF_DIS = OFF_BC + HH;                         // [NROWS] f32
constexpr size_t OFF_G   = OFF_DIS + NROWS;                     // [BB*HH] f32 pool sums (atomics)
// stats: stage0 (x): 512 single-bucket; stages 1..3 (h): 8 buckets x 512 each
constexpr size_t OFF_ST  = OFF_G + BB*HH;
constexpr size_t ST_SIZE = 512 + 3*8*512;                       // 12800 floats
constexpr size_t OFF_FLAG= OFF_ST + ST_SIZE;                    // 1 int (1 => inputs f32)
constexpr size_t OFF_TICK= OFF_FLAG + 1;                        // 4 ints (last-block tickets)
constexpr size_t OFF_CNT = OFF_TICK + 4;                        // [NROWS] int32
constexpr size_t OFF_COLS= OFF_CNT + NROWS;                     // [NROWS*MAXC] u16

typedef __attribute__((ext_vector_type(8))) short short8;   // 8 bf16 in 4 VGPRs
typedef __attribute__((ext_vector_type(4))) float f32x4;
typedef __attribute__((ext_vector_type(4))) unsigned int u32x4;
typedef __attribute__((ext_vector_type(2))) unsigned int u32x2;

static __device__ __forceinline__ float bf(const __hip_bfloat16 v) {
    return __bfloat162float(v);
}
static __device__ __forceinline__ float ldin(const void* p, size_t i, int isf) {
    return isf ? ((const float*)p)[i]
               : __bfloat162float(((const __hip_bfloat16*)p)[i]);
}
static __host__ __device__ __forceinline__ float* stage_h(float* ws, int s /*0..2*/) {
    return ws + OFF_ST + 512 + (size_t)s*8*512;
}
// coherent cross-XCD read of an atomically-accumulated float (RMW with 0)
static __device__ __forceinline__ float aread(float* p) {
    return atomicAdd(p, 0.0f);
}
static __device__ __forceinline__ float blo(unsigned int u) {
    union { unsigned int x; float f; } v; v.x = u << 16; return v.f;
}
static __device__ __forceinline__ float bhi(unsigned int u) {
    union { unsigned int x; float f; } v; v.x = u & 0xFFFF0000u; return v.f;
}
static __device__ __forceinline__ unsigned int packbf(float a, float b) {
    union { unsigned int u; __hip_bfloat16 h[2]; } p;
    p.h[0] = __float2bfloat16(a); p.h[1] = __float2bfloat16(b);
    return p.u;
}

// Detect input dtype; zero pool + stat accumulators + tickets.
__global__ void detect_and_zero(const unsigned int* __restrict__ adjw, float* ws) {
    __shared__ int evid;
    int tid = threadIdx.x;
    if (tid == 0) evid = 0;
    __syncthreads();
    int local = 0;
    for (int k = tid; k < 16384; k += 256) {
        unsigned int w = adjw[k];
        if ((w & 0xFFFFu) == 0x3F80u) local++;   // bf16-packed even-index 1.0
    }
    if (local) atomicAdd(&evid, local);
    // pool + stats + flag + ticks are contiguous: zero them all, flag rewritten below
    size_t ztot = BB*HH + ST_SIZE + 1 + 4;
    for (size_t k = tid; k < ztot; k += 256) ws[OFF_G + k] = 0.f;
    __syncthreads();
    if (tid == 0) ((int*)ws)[OFF_FLAG] = (evid == 0) ? 1 : 0;
}

// Role-split: blocks [0,NROWS) build graph rows; blocks [NROWS,NROWS+256) x-stats.
// LAST block (device ticket) folds BN(x) into W_feat -> WPF/BF.
__global__ __launch_bounds__(256) void phase1(const void* __restrict__ adj,
                                              const void* __restrict__ x,
                                              const void* __restrict__ W_feat,
                                              const void* __restrict__ bnf_g,
                                              const void* __restrict__ bnf_b,
                                              float* ws) {
    const int isf = ((const int*)ws)[OFF_FLAG];
    int tid = threadIdx.x;
    if (blockIdx.x < NROWS) {
        int row = blockIdx.x;
        int i   = row & (NN - 1);
        __shared__ int cnt_s;
        __shared__ unsigned short colbuf[MAXC];
        if (tid == 0) cnt_s = 0;
        __syncthreads();
        int j0 = tid*4;
        unsigned int bits[4];
        if (isf) {
            u32x4 v = *(const u32x4*)((const unsigned int*)adj + (size_t)row*NN + j0);
            bits[0]=v[0]; bits[1]=v[1]; bits[2]=v[2]; bits[3]=v[3];
        } else {
            u32x2 v = *(const u32x2*)((const unsigned short*)adj + (size_t)row*NN + j0);
            bits[0]=(v[0]&0xFFFFu); bits[1]=(v[0]>>16); bits[2]=(v[1]&0xFFFFu); bits[3]=(v[1]>>16);
        }
        #pragma unroll
        for (int e = 0; e < 4; ++e) {
            int j = j0 + e;
            if ((bits[e] << 1) != 0u || j == i) {   // value != +-0  (or self loop)
                int p = atomicAdd(&cnt_s, 1);
                if (p < MAXC) colbuf[p] = (unsigned short)j;
            }
        }
        __syncthreads();
        int c = cnt_s; if (c > MAXC) c = MAXC;
        if (tid == 0) {
            ((int*)(ws + OFF_CNT))[row] = c;
            ws[OFF_DIS + row] = rsqrtf((float)cnt_s);   // deg >= 1 (self loop)
        }
        unsigned short* cols = (unsigned short*)(ws + OFF_COLS);
        for (int k = tid; k < c; k += 256) cols[(size_t)row*MAXC + k] = colbuf[k];
    } else {
        int b2 = blockIdx.x - NROWS;          // 0..255
        int f = tid & (FF-1), half = tid >> 7;
        int r0 = b2*64 + half*32;
        float s = 0.f, sq = 0.f;
        for (int r = 0; r < 32; ++r) {
            float v = ldin(x, (size_t)(r0 + r)*FF + f, isf);
            s += v; sq += v*v;
        }
        atomicAdd(&ws[OFF_ST + f], s);
        atomicAdd(&ws[OFF_ST + 256 + f], sq);
    }
    // ---- last-block fold of feat BN into weights ----
    __shared__ int tk;
    __shared__ float fa[FF], fc[FF], fb[HH];
    __syncthreads();
    if (tid == 0) { __threadfence(); tk = atomicAdd(&((int*)ws)[OFF_TICK + 0], 1); }
    __syncthreads();
    if (tk != NROWS + 256 - 1) return;
    if (tid < FF) {
        float s = aread(&ws[OFF_ST + tid]);
        float q = aread(&ws[OFF_ST + 256 + tid]);
        float m = s * (1.f/NROWS);
        float var = q * (1.f/NROWS) - m*m;
        float a = ldin(bnf_g, tid, isf) * rsqrtf(var + EPSV);
        fa[tid] = a;
        fc[tid] = ldin(bnf_b, tid, isf) - m*a;
    }
    for (int i = tid; i < HH; i += 256) fb[i] = 0.f;
    __syncthreads();
    __hip_bfloat16* wpf = (__hip_bfloat16*)(ws + OFF_WPF);
    for (int idx = tid; idx < HH*FF; idx += 256) {
        int n = idx >> 7, k = idx & (FF-1);
        float wv = ldin(W_feat, (size_t)k*HH + n, isf);
        wpf[idx] = __float2bfloat16(fa[k]*wv);
        atomicAdd(&fb[n], fc[k]*wv);
    }
    __syncthreads();
    if (tid < HH) ws[OFF_BF + tid] = fb[tid];
}

// C = A[M x K] @ W'T[N x K]^T + bias via MFMA 16x16x32 bf16.
// Block 256thr = 4 waves as 2x2: wave = 16 rows x 96 cols. grid = NROWS/32 = 512.
// XCD-locality swizzle: batch = blockIdx & 15.
// MODE 0 (feat): A=x (isf dtype), H0 = bf16(relu(C)); fused stage-0 stats; last
//                block folds BN into convs_W[0] -> WPC/BC.
// MODE 1 (conv): A=H0 bf16, Z' = bf16(dis[row]*C).
template<int K, int MODE>
__global__ __launch_bounds__(256) void gemm_mfma(const void* __restrict__ A,
                                                 const __hip_bfloat16* __restrict__ BT,
                                                 const float* __restrict__ bias,
                                                 const void* __restrict__ convs_W,
                                                 const void* __restrict__ bnc_g,
                                                 const void* __restrict__ bnc_b,
                                                 float* __restrict__ ws) {
    const int isf = ((const int*)ws)[OFF_FLAG];
    int tid = threadIdx.x;
    int lane = tid & 63, w = tid >> 6;
    int wr = w & 1, wc = w >> 1;
    int bi = blockIdx.x;
    int batch = bi & 15, seg = bi >> 4;               // seg 0..31
    int row0 = batch*NN + seg*32 + wr*16;
    int col0 = wc*96;
    int m    = lane & 15, quad = lane >> 4;
    f32x4 acc[6];
    #pragma unroll
    for (int t = 0; t < 6; ++t) acc[t] = f32x4{0.f,0.f,0.f,0.f};
    float bv[6];
    #pragma unroll
    for (int t = 0; t < 6; ++t) bv[t] = bias[col0 + t*16 + m];
    #pragma unroll
    for (int kb = 0; kb < K/32; ++kb) {
        short8 a;
        if (MODE == 0 && isf) {
            const float* Ar = (const float*)A + (size_t)(row0+m)*K + kb*32 + quad*8;
            f32x4 v0 = *(const f32x4*)Ar;
            f32x4 v1 = *(const f32x4*)(Ar + 4);
            union { short8 s8; __hip_bfloat16 h[8]; } u;
            #pragma unroll
            for (int e = 0; e < 4; ++e) {
                u.h[e]   = __float2bfloat16(v0[e]);
                u.h[e+4] = __float2bfloat16(v1[e]);
            }
            a = u.s8;
        } else {
            a = *(const short8*)((const __hip_bfloat16*)A +
                                 (size_t)(row0+m)*K + kb*32 + quad*8);
        }
        #pragma unroll
        for (int t = 0; t < 6; ++t) {
            short8 b = *(const short8*)(BT + (size_t)(col0 + t*16+m)*K + kb*32 + quad*8);
            acc[t] = __builtin_amdgcn_mfma_f32_16x16x32_bf16(a, b, acc[t], 0, 0, 0);
        }
    }
    if (MODE == 0) {
        __shared__ float sh[2*HH];
        __shared__ float shb[HH];
        __shared__ int tk;
        for (int i = tid; i < 2*HH; i += 256) sh[i] = 0.f;
        __syncthreads();
        __hip_bfloat16* H0 = (__hip_bfloat16*)(ws + OFF_H0);
        #pragma unroll
        for (int t = 0; t < 6; ++t) {
            int ch = col0 + t*16 + m;
            float s = 0.f, sq = 0.f;
            #pragma unroll
            for (int r = 0; r < 4; ++r) {
                float o = fmaxf(acc[t][r] + bv[t], 0.f);
                H0[(size_t)(row0 + quad*4 + r)*HH + ch] = __float2bfloat16(o);
                s += o; sq += o*o;
            }
            atomicAdd(&sh[ch], s);
            atomicAdd(&sh[HH + ch], sq);
        }
        __syncthreads();
        float* st = stage_h(ws, 0) + (size_t)(bi & 7)*512;
        if (tid < HH) {
            atomicAdd(&st[tid], sh[tid]);
            atomicAdd(&st[256 + tid], sh[HH + tid]);
        }
        // ---- last-block fold of conv layer 0 ----
        __syncthreads();
        if (tid == 0) { __threadfence(); tk = atomicAdd(&((int*)ws)[OFF_TICK + 1], 1); }
        __syncthreads();
        if (tk != NROWS/32 - 1) return;
        if (tid < HH) {
            float* s0 = stage_h(ws, 0);
            float s = 0.f, q = 0.f;
            #pragma unroll
            for (int b = 0; b < 8; ++b) {
                s += aread(&s0[b*512 + tid]);
                q += aread(&s0[b*512 + 256 + tid]);
            }
            float mm = s * (1.f/NROWS);
            float var = q * (1.f/NROWS) - mm*mm;
            float a = ldin(bnc_g, tid, isf) * rsqrtf(var + EPSV);
            sh[tid] = a;
            sh[HH + tid] = ldin(bnc_b, tid, isf) - mm*a;
        }
        for (int i = tid; i < HH; i += 256) shb[i] = 0.f;
        __syncthreads();
        __hip_bfloat16* wpc = (__hip_bfloat16*)(ws + OFF_WPC);
        for (int idx = tid; idx < HH*HH; idx += 256) {
            int n = idx / HH, k = idx - n*HH;
            float wv = ldin(convs_W, (size_t)k*HH + n, isf);
            wpc[idx] = __float2bfloat16(sh[k]*wv);
            atomicAdd(&shb[n], sh[HH + k]*wv);
        }
        __syncthreads();
        if (tid < HH) ws[OFF_BC + tid] = shb[tid];
    } else {
        const float* dis = ws + OFF_DIS;
        __hip_bfloat16* Z = (__hip_bfloat16*)(ws + OFF_ZB);
        float sc[4];
        #pragma unroll
        for (int r = 0; r < 4; ++r) sc[r] = dis[row0 + quad*4 + r];
        #pragma unroll
        for (int t = 0; t < 6; ++t)
            #pragma unroll
            for (int r = 0; r < 4; ++r)
                Z[(size_t)(row0 + quad*4 + r)*HH + col0 + t*16 + m] =
                    __float2bfloat16((acc[t][r] + bv[t]) * sc[r]);
    }
}

// LDS-staged SpMM: H0 = bf16(relu( dis_i * sum_{j in N(i)} Z'[j] + bias )).
// grid 192 = batch(16) x [slice(6) x half(2)]; block 512 thr. Z slice in LDS (64 KB).
// Fused stats (8-bucket) for layers 0,1 (+ last-block fold of conv layer l+1);
// pool sums for layer 2.
__global__ __launch_bounds__(512) void spmm(const void* __restrict__ bias, int layer,
                                            float* __restrict__ stat_out, int is_pool,
                                            const void* __restrict__ convs_W,
                                            const void* __restrict__ bnc_g,
                                            const void* __restrict__ bnc_b,
                                            float* ws) {
    __shared__ unsigned int Zs[NN*16];   // exactly 64 KB
    __shared__ int tk;
    const int isf = ((const int*)ws)[OFF_FLAG];
    int tid = threadIdx.x;
    int bi = blockIdx.x;
    int batch = bi & 15;
    int rest  = bi >> 4;          // 0..11
    int slice = rest % 6;         // channel slice: c0 = slice*32
    int half  = rest / 6;         // rows [half*512, half*512+512)
    int c0 = slice*32;
    const unsigned int* Zu = (const unsigned int*)(ws + OFF_ZB)
                             + (size_t)batch*NN*96 + c0/2;
    for (int i = tid; i < NN*16; i += 512) {
        int r = i >> 4, u = i & 15;
        Zs[i] = Zu[(size_t)r*96 + u];
    }
    __syncthreads();
    int d = tid & 7, rslot = tid >> 3;
    const float* dis = ws + OFF_DIS;
    const int* cnt = (const int*)(ws + OFF_CNT);
    const unsigned short* cols = (const unsigned short*)(ws + OFF_COLS);
    unsigned int* H0u = (unsigned int*)(ws + OFF_H0);
    float bch[4];
    #pragma unroll
    for (int e = 0; e < 4; ++e)
        bch[e] = ldin(bias, (size_t)layer*HH + c0 + d*4 + e, isf);
    float s_acc[4] = {0.f,0.f,0.f,0.f}, q_acc[4] = {0.f,0.f,0.f,0.f};
    for (int it = 0; it < 8; ++it) {
        int row = batch*NN + half*512 + it*64 + rslot;
        int c = cnt[row];
        const unsigned short* cl = cols + (size_t)row*MAXC;
        float a0=0.f, a1=0.f, a2=0.f, a3=0.f;
        int k = 0;
        for (; k + 8 <= c; k += 8) {
            u32x4 cw = *(const u32x4*)(cl + k);
            int j[8];
            j[0]=(int)(cw[0]&0xFFFFu); j[1]=(int)(cw[0]>>16);
            j[2]=(int)(cw[1]&0xFFFFu); j[3]=(int)(cw[1]>>16);
            j[4]=(int)(cw[2]&0xFFFFu); j[5]=(int)(cw[2]>>16);
            j[6]=(int)(cw[3]&0xFFFFu); j[7]=(int)(cw[3]>>16);
            u32x2 z[8];
            #pragma unroll
            for (int e = 0; e < 8; ++e)
                z[e] = *(const u32x2*)(&Zs[j[e]*16 + d*2]);
            #pragma unroll
            for (int e = 0; e < 8; ++e) {
                a0 += blo(z[e][0]); a1 += bhi(z[e][0]);
                a2 += blo(z[e][1]); a3 += bhi(z[e][1]);
            }
        }
        for (; k < c; ++k) {
            u32x2 z = *(const u32x2*)(&Zs[(int)cl[k]*16 + d*2]);
            a0 += blo(z[0]); a1 += bhi(z[0]);
            a2 += blo(z[1]); a3 += bhi(z[1]);
        }
        float dd = dis[row];
        float o0 = fmaxf(dd*a0 + bch[0], 0.f);
        float o1 = fmaxf(dd*a1 + bch[1], 0.f);
        float o2 = fmaxf(dd*a2 + bch[2], 0.f);
        float o3 = fmaxf(dd*a3 + bch[3], 0.f);
        u32x2 outw; outw[0] = packbf(o0,o1); outw[1] = packbf(o2,o3);
        *(u32x2*)(&H0u[(size_t)row*96 + c0/2 + d*2]) = outw;
        s_acc[0]+=o0; s_acc[1]+=o1; s_acc[2]+=o2; s_acc[3]+=o3;
        q_acc[0]+=o0*o0; q_acc[1]+=o1*o1; q_acc[2]+=o2*o2; q_acc[3]+=o3*o3;
    }
    // reduce over rslot within each wave (lanes differing in bits 3..5 share d)
    #pragma unroll
    for (int e = 0; e < 4; ++e) {
        #pragma unroll
        for (int mask = 8; mask < 64; mask <<= 1) {
            s_acc[e] += __shfl_xor(s_acc[e], mask, 64);
            q_acc[e] += __shfl_xor(q_acc[e], mask, 64);
        }
    }
    if ((tid & 63) < 8) {
        if (is_pool) {
            #pragma unroll
            for (int e = 0; e < 4; ++e)
                atomicAdd(&ws[OFF_G + (size_t)batch*HH + c0 + d*4 + e], s_acc[e]);
        } else {
            float* st = stat_out + (bi & 7)*512;
            #pragma unroll
            for (int e = 0; e < 4; ++e) {
                atomicAdd(&st[c0 + d*4 + e],       s_acc[e]);
                atomicAdd(&st[256 + c0 + d*4 + e], q_acc[e]);
            }
        }
    }
    if (is_pool) return;
    // ---- last-block fold of conv layer (layer+1) ----
    __syncthreads();
    if (tid == 0) { __threadfence(); tk = atomicAdd(&((int*)ws)[OFF_TICK + 2 + layer], 1); }
    __syncthreads();
    if (tk != 192 - 1) return;
    float* fa = (float*)Zs;              // [HH]
    float* fc = fa + HH;                 // [HH]
    float* fb = fa + 2*HH;               // [HH]
    int l1 = layer + 1;
    if (tid < HH) {
        float* s0 = stat_out;
        float s = 0.f, q = 0.f;
        #pragma unroll
        for (int b = 0; b < 8; ++b) {
            s += aread(&s0[b*512 + tid]);
            q += aread(&s0[b*512 + 256 + tid]);
        }
        float mm = s * (1.f/NROWS);
        float var = q * (1.f/NROWS) - mm*mm;
        float a = ldin(bnc_g, (size_t)l1*HH + tid, isf) * rsqrtf(var + EPSV);
        fa[tid] = a;
        fc[tid] = ldin(bnc_b, (size_t)l1*HH + tid, isf) - mm*a;
    }
    for (int i = tid; i < HH; i += 512) fb[i] = 0.f;
    __syncthreads();
    __hip_bfloat16* wpc = (__hip_bfloat16*)(ws + OFF_WPC);
    for (int idx = tid; idx < HH*HH; idx += 512) {
        int n = idx / HH, k = idx - n*HH;
        float wv = ldin(convs_W, (size_t)l1*HH*HH + (size_t)k*HH + n, isf);
        wpc[idx] = __float2bfloat16(fa[k]*wv);
        atomicAdd(&fb[n], fc[k]*wv);
    }
    __syncthreads();
    if (tid < HH) ws[OFF_BC + tid] = fb[tid];
}

// BN -> relu(linear) -> BN -> classifier -> log_softmax. One block, 768 thr.
__global__ __launch_bounds__(768) void tail(
                     const void* __restrict__ fc_g,  const void* __restrict__ fc_b,
                     const void* __restrict__ lin_W, const void* __restrict__ lin_b,
                     const void* __restrict__ hid_g, const void* __restrict__ hid_b,
                     const void* __restrict__ cls_W, const void* __restrict__ cls_b,
                     void* __restrict__ out, const float* ws) {
    __shared__ float g1[BB][HH];
    __shared__ float g2[BB][HH];
    __shared__ __hip_bfloat16 Wl[HH*HH];
    __shared__ float logits[BB][10];
    __shared__ float lse[BB];
    int tid = threadIdx.x;
    const int isf = ((const int*)ws)[OFF_FLAG];
    const float* g = ws + OFF_G;   // sums over N; scale by 1/NN
    if (isf) {
        const float* Wp = (const float*)lin_W;
        for (int i = tid; i < HH*HH; i += 768) Wl[i] = __float2bfloat16(Wp[i]);
    } else {
        const __hip_bfloat16* Wp = (const __hip_bfloat16*)lin_W;
        for (int i = tid; i < HH*HH; i += 768) Wl[i] = Wp[i];
    }
    if (tid < HH) {
        float s = 0.f, sq = 0.f;
        for (int b = 0; b < BB; ++b) {
            float v = g[b*HH + tid] * (1.f/NN);
            s += v; sq += v*v;
        }
        float m = s*(1.f/BB), var = sq*(1.f/BB) - m*m;
        float a = ldin(fc_g, tid, isf) * rsqrtf(var + EPSV);
        float c = ldin(fc_b, tid, isf) - m*a;
        for (int b = 0; b < BB; ++b) g1[b][tid] = g[b*HH + tid]*(1.f/NN)*a + c;
    }
    __syncthreads();
    {
        int n = tid % HH, bg = tid / HH;
        float lb = ldin(lin_b, n, isf);
        float a0 = lb, a1 = lb, a2 = lb, a3 = lb;
        int b0 = bg*4;
        for (int k = 0; k < HH; ++k) {
            float wv = bf(Wl[k*HH + n]);
            a0 += g1[b0+0][k]*wv;
            a1 += g1[b0+1][k]*wv;
            a2 += g1[b0+2][k]*wv;
            a3 += g1[b0+3][k]*wv;
        }
        g2[b0+0][n] = fmaxf(a0, 0.f);
        g2[b0+1][n] = fmaxf(a1, 0.f);
        g2[b0+2][n] = fmaxf(a2, 0.f);
        g2[b0+3][n] = fmaxf(a3, 0.f);
    }
    __syncthreads();
    if (tid < HH) {
        float s = 0.f, sq = 0.f;
        for (int b = 0; b < BB; ++b) { float v = g2[b][tid]; s += v; sq += v*v; }
        float m = s*(1.f/BB), var = sq*(1.f/BB) - m*m;
        float a = ldin(hid_g, tid, isf) * rsqrtf(var + EPSV);
        float c = ldin(hid_b, tid, isf) - m*a;
        for (int b = 0; b < BB; ++b) g2[b][tid] = g2[b][tid]*a + c;
    }
    __syncthreads();
    if (tid < BB*10) {
        int b = tid/10, k = tid%10;
        float acc = ldin(cls_b, k, isf);
        for (int h = 0; h < HH; ++h) acc += g2[b][h] * ldin(cls_W, (size_t)h*10 + k, isf);
        logits[b][k] = acc;
    }
    __syncthreads();
    if (tid < BB) {
        float m = -1e30f;
        for (int k = 0; k < 10; ++k) m = fmaxf(m, logits[tid][k]);
        float s = 0.f;
        for (int k = 0; k < 10; ++k) s += expf(logits[tid][k] - m);
        lse[tid] = m + logf(s);
    }
    __syncthreads();
    if (tid < BB*10) {
        int b = tid/10;
        float v = logits[b][tid%10] - lse[b];
        if (isf) ((float*)out)[tid] = v;
        else     ((__hip_bfloat16*)out)[tid] = __float2bfloat16(v);
    }
}

extern "C" void kernel_launch(void* const* d_in, const int* in_sizes, int n_in,
                              void* d_out, int out_size, void* d_ws, size_t ws_size,
                              hipStream_t stream) {
    const void* x       = d_in[0];
    const void* adj     = d_in[1];
    const void* bnf_g   = d_in[2];
    const void* bnf_b   = d_in[3];
    const void* W_feat  = d_in[4];
    const void* bnc_g   = d_in[5];
    const void* bnc_b   = d_in[6];
    const void* convs_W = d_in[7];
    const void* convs_b = d_in[8];
    const void* fc_g    = d_in[9];
    const void* fc_b    = d_in[10];
    const void* lin_W   = d_in[11];
    const void* lin_b   = d_in[12];
    const void* hid_g   = d_in[13];
    const void* hid_b   = d_in[14];
    const void* cls_W   = d_in[15];
    const void* cls_b   = d_in[16];

    float* ws = (float*)d_ws;
    const __hip_bfloat16* WPF = (const __hip_bfloat16*)(ws + OFF_WPF);
    const __hip_bfloat16* WPC = (const __hip_bfloat16*)(ws + OFF_WPC);

    detect_and_zero<<<1, 256, 0, stream>>>((const unsigned int*)adj, ws);
    phase1<<<NROWS + 256, 256, 0, stream>>>(adj, x, W_feat, bnf_g, bnf_b, ws);
    gemm_mfma<FF, 0><<<NROWS/32, 256, 0, stream>>>(x, WPF, ws + OFF_BF,
                                                   convs_W, bnc_g, bnc_b, ws);
    for (int l = 0; l < 3; ++l) {
        gemm_mfma<HH, 1><<<NROWS/32, 256, 0, stream>>>(
            (const void*)(ws + OFF_H0), WPC, ws + OFF_BC,
            convs_W, bnc_g, bnc_b, ws);
        spmm<<<192, 512, 0, stream>>>(convs_b, l,
            (l < 2) ? stage_h(ws, l + 1) : nullptr, (l == 2) ? 1 : 0,
            convs_W, bnc_g, bnc_b, ws);
    }
    tail<<<1, 768, 0, stream>>>(fc_g, fc_b, lin_W, lin_b,
                                hid_g, hid_b, cls_W, cls_b, d_out, ws);
}

// Round 12
// 426.888 us; speedup vs baseline: 2.7249x; 2.2333x over previous
//
#include <hip/hip_runtime.h>
#include <hip/hip_bf16.h>

#define BB 16
#define NN 1024
#define FF 128
#define HH 192
#define NROWS (BB*NN)
#define MAXC 128
#define EPSV 1e-5f

// workspace layout, in float (4B) units (~17 MB total)
constexpr size_t OFF_H0  = 0;                                   // [NROWS*HH] bf16 (h, post-relu)
constexpr size_t OFF_ZB  = OFF_H0 + (size_t)NROWS*HH/2;         // [NROWS*HH] bf16 (Z' = dis_j*(hW'+bias))
constexpr size_t OFF_DIS = OFF_ZB + (size_t)NROWS*HH/2;         // [NROWS] f32
constexpr size_t OFF_G   = OFF_DIS + NROWS;                     // [BB*HH] f32 pool sums (atomics)
// stats: stage0 (x): 512 single-bucket; stages 1..3 (h): 8 buckets x 512 each
constexpr size_t OFF_ST  = OFF_G + BB*HH;
constexpr size_t ST_SIZE = 512 + 3*8*512;                       // 12800 floats
constexpr size_t OFF_FLAG= OFF_ST + ST_SIZE;                    // 1 int (1 => inputs f32)
constexpr size_t OFF_CNT = OFF_FLAG + 1;                        // [NROWS] int32
constexpr size_t OFF_COLS= OFF_CNT + NROWS;                     // [NROWS*MAXC] u16

typedef __attribute__((ext_vector_type(8))) short short8;   // 8 bf16 in 4 VGPRs
typedef __attribute__((ext_vector_type(4))) float f32x4;
typedef __attribute__((ext_vector_type(4))) unsigned int u32x4;
typedef __attribute__((ext_vector_type(2))) unsigned int u32x2;

static __device__ __forceinline__ float bf(const __hip_bfloat16 v) {
    return __bfloat162float(v);
}
static __device__ __forceinline__ float ldin(const void* p, size_t i, int isf) {
    return isf ? ((const float*)p)[i]
               : __bfloat162float(((const __hip_bfloat16*)p)[i]);
}
static __host__ __device__ __forceinline__ float* stage_h(float* ws, int s /*0..2*/) {
    return ws + OFF_ST + 512 + (size_t)s*8*512;
}
static __device__ __forceinline__ float blo(unsigned int u) {
    union { unsigned int x; float f; } v; v.x = u << 16; return v.f;
}
static __device__ __forceinline__ float bhi(unsigned int u) {
    union { unsigned int x; float f; } v; v.x = u & 0xFFFF0000u; return v.f;
}
static __device__ __forceinline__ unsigned int packbf(float a, float b) {
    union { unsigned int u; __hip_bfloat16 h[2]; } p;
    p.h[0] = __float2bfloat16(a); p.h[1] = __float2bfloat16(b);
    return p.u;
}

// Detect input dtype from adj bit patterns; zero stat accumulators + pool sums.
__global__ void detect_and_zero(const unsigned int* __restrict__ adjw, float* ws) {
    __shared__ int evid;
    int tid = threadIdx.x;
    if (tid == 0) evid = 0;
    __syncthreads();
    int local = 0;
    for (int k = tid; k < 16384; k += 256) {
        unsigned int w = adjw[k];
        if ((w & 0xFFFFu) == 0x3F80u) local++;   // bf16-packed even-index 1.0
    }
    if (local) atomicAdd(&evid, local);
    for (size_t k = tid; k < ST_SIZE; k += 256) ws[OFF_ST + k] = 0.f;
    for (int k = tid; k < BB*HH; k += 256) ws[OFF_G + k] = 0.f;
    __syncthreads();
    if (tid == 0) ((int*)ws)[OFF_FLAG] = (evid == 0) ? 1 : 0;
}

// Role-split kernel: blocks [0,NROWS) build graph rows; blocks [NROWS, NROWS+256)
// compute per-feature stats of x (stage 0 single-bucket).
__global__ __launch_bounds__(256) void phase1(const void* __restrict__ adj,
                                              const void* __restrict__ x, float* ws) {
    const int isf = ((const int*)ws)[OFF_FLAG];
    int tid = threadIdx.x;
    if (blockIdx.x < NROWS) {
        int row = blockIdx.x;
        int i   = row & (NN - 1);
        __shared__ int cnt_s;
        __shared__ unsigned short colbuf[MAXC];
        if (tid == 0) cnt_s = 0;
        __syncthreads();
        int j0 = tid*4;
        unsigned int bits[4];
        if (isf) {
            u32x4 v = *(const u32x4*)((const unsigned int*)adj + (size_t)row*NN + j0);
            bits[0]=v[0]; bits[1]=v[1]; bits[2]=v[2]; bits[3]=v[3];
        } else {
            u32x2 v = *(const u32x2*)((const unsigned short*)adj + (size_t)row*NN + j0);
            bits[0]=(v[0]&0xFFFFu); bits[1]=(v[0]>>16); bits[2]=(v[1]&0xFFFFu); bits[3]=(v[1]>>16);
        }
        #pragma unroll
        for (int e = 0; e < 4; ++e) {
            int j = j0 + e;
            if ((bits[e] << 1) != 0u || j == i) {   // value != +-0  (or self loop)
                int p = atomicAdd(&cnt_s, 1);
                if (p < MAXC) colbuf[p] = (unsigned short)j;
            }
        }
        __syncthreads();
        int c = cnt_s; if (c > MAXC) c = MAXC;
        if (tid == 0) {
            ((int*)(ws + OFF_CNT))[row] = c;
            ws[OFF_DIS + row] = rsqrtf((float)cnt_s);   // deg >= 1 (self loop)
        }
        unsigned short* cols = (unsigned short*)(ws + OFF_COLS);
        for (int k = tid; k < c; k += 256) cols[(size_t)row*MAXC + k] = colbuf[k];
    } else {
        int b2 = blockIdx.x - NROWS;          // 0..255
        int f = tid & (FF-1), half = tid >> 7;
        int r0 = b2*64 + half*32;
        float s = 0.f, sq = 0.f;
        for (int r = 0; r < 32; ++r) {
            float v = ldin(x, (size_t)(r0 + r)*FF + f, isf);
            s += v; sq += v*v;
        }
        atomicAdd(&ws[OFF_ST + f], s);
        atomicAdd(&ws[OFF_ST + 256 + f], sq);
    }
}

// C = A[M x K] @ W'T[N x K]^T + bias via MFMA 16x16x32 bf16, with CONSUMER-SIDE
// BN fold: each block redundantly folds BN(stats) into an LDS copy of W'T
// (+8-elem pad for bank-conflict-free ds_read_b128) and computes bias = c@W.
// Stats are read with plain loads (previous kernel's atomics are visible across
// the dispatch boundary). No tickets, no fences.
// Block 256thr = 4 waves as 2x2: wave = 16 rows x 96 cols. grid = NROWS/32 = 512.
// XCD-locality swizzle: batch = blockIdx & 15.
// MODE 0 (feat): A=x (isf dtype), W=W_feat, stats=OFF_ST single-bucket;
//                out H0 = bf16(relu(C)); fused stage-0 stats.
// MODE 1 (conv): A=H0 bf16, W=convs_W[layer], stats=stage_h(layer) 8-bucket;
//                out Z' = bf16(dis[row] * C).
template<int K, int MODE>
__global__ __launch_bounds__(256) void gemm_mfma(const void* __restrict__ A,
                                                 const void* __restrict__ W_src,
                                                 const void* __restrict__ g_src,
                                                 const void* __restrict__ b_src,
                                                 int layer,
                                                 float* __restrict__ ws) {
    constexpr int KP = K + 8;                       // padded LDS stride (bf16 elems)
    __shared__ __hip_bfloat16 BTs[HH*KP];           // mode1: 76.8 KB; mode0: 52.2 KB
    __shared__ float afold[K], cfold[K];
    __shared__ float biasS[HH];
    __shared__ float sh[2*HH];                      // mode0 stats staging
    const int isf = ((const int*)ws)[OFF_FLAG];
    int tid = threadIdx.x;

    // ---- fold BN into LDS weights ----
    if (tid < K) {
        float s, q;
        if (MODE == 0) {
            s = ws[OFF_ST + tid];
            q = ws[OFF_ST + 256 + tid];
        } else {
            const float* st = stage_h(ws, layer);
            s = 0.f; q = 0.f;
            #pragma unroll
            for (int b = 0; b < 8; ++b) { s += st[b*512 + tid]; q += st[b*512 + 256 + tid]; }
        }
        float m = s * (1.f/NROWS);
        float var = q * (1.f/NROWS) - m*m;
        float a = ldin(g_src, (size_t)layer*K + tid, isf) * rsqrtf(var + EPSV);
        afold[tid] = a;
        cfold[tid] = ldin(b_src, (size_t)layer*K + tid, isf) - m*a;
    }
    __syncthreads();
    size_t w0 = (size_t)layer*K*HH;
    if (tid < HH) {                                 // bias: column-n dot (L2-hot)
        float b = 0.f;
        for (int k = 0; k < K; ++k)
            b += cfold[k] * ldin(W_src, w0 + (size_t)k*HH + tid, isf);
        biasS[tid] = b;
    }
    for (int idx = tid; idx < K*HH; idx += 256) {   // n-fastest: coalesced W reads
        int k = idx / HH, n = idx - k*HH;
        BTs[n*KP + k] = __float2bfloat16(afold[k] * ldin(W_src, w0 + (size_t)idx, isf));
    }
    __syncthreads();

    // ---- MFMA main loop ----
    int lane = tid & 63, w = tid >> 6;
    int wr = w & 1, wc = w >> 1;
    int bi = blockIdx.x;
    int batch = bi & 15, seg = bi >> 4;               // seg 0..31
    int row0 = batch*NN + seg*32 + wr*16;
    int col0 = wc*96;
    int m    = lane & 15, quad = lane >> 4;
    f32x4 acc[6];
    #pragma unroll
    for (int t = 0; t < 6; ++t) acc[t] = f32x4{0.f,0.f,0.f,0.f};
    float bv[6];
    #pragma unroll
    for (int t = 0; t < 6; ++t) bv[t] = biasS[col0 + t*16 + m];
    #pragma unroll
    for (int kb = 0; kb < K/32; ++kb) {
        short8 a;
        if (MODE == 0 && isf) {
            const float* Ar = (const float*)A + (size_t)(row0+m)*K + kb*32 + quad*8;
            f32x4 v0 = *(const f32x4*)Ar;
            f32x4 v1 = *(const f32x4*)(Ar + 4);
            union { short8 s8; __hip_bfloat16 h[8]; } u;
            #pragma unroll
            for (int e = 0; e < 4; ++e) {
                u.h[e]   = __float2bfloat16(v0[e]);
                u.h[e+4] = __float2bfloat16(v1[e]);
            }
            a = u.s8;
        } else {
            a = *(const short8*)((const __hip_bfloat16*)A +
                                 (size_t)(row0+m)*K + kb*32 + quad*8);
        }
        #pragma unroll
        for (int t = 0; t < 6; ++t) {
            short8 b = *(const short8*)(BTs + (size_t)(col0 + t*16 + m)*KP + kb*32 + quad*8);
            acc[t] = __builtin_amdgcn_mfma_f32_16x16x32_bf16(a, b, acc[t], 0, 0, 0);
        }
    }
    if (MODE == 0) {
        for (int i = tid; i < 2*HH; i += 256) sh[i] = 0.f;
        __syncthreads();
        __hip_bfloat16* H0 = (__hip_bfloat16*)(ws + OFF_H0);
        #pragma unroll
        for (int t = 0; t < 6; ++t) {
            int ch = col0 + t*16 + m;
            float s = 0.f, sq = 0.f;
            #pragma unroll
            for (int r = 0; r < 4; ++r) {
                float o = fmaxf(acc[t][r] + bv[t], 0.f);
                H0[(size_t)(row0 + quad*4 + r)*HH + ch] = __float2bfloat16(o);
                s += o; sq += o*o;
            }
            atomicAdd(&sh[ch], s);
            atomicAdd(&sh[HH + ch], sq);
        }
        __syncthreads();
        float* st = stage_h(ws, 0) + (size_t)(bi & 7)*512;
        if (tid < HH) {
            atomicAdd(&st[tid], sh[tid]);
            atomicAdd(&st[256 + tid], sh[HH + tid]);
        }
    } else {
        const float* dis = ws + OFF_DIS;
        __hip_bfloat16* Z = (__hip_bfloat16*)(ws + OFF_ZB);
        float sc[4];
        #pragma unroll
        for (int r = 0; r < 4; ++r) sc[r] = dis[row0 + quad*4 + r];
        #pragma unroll
        for (int t = 0; t < 6; ++t)
            #pragma unroll
            for (int r = 0; r < 4; ++r)
                Z[(size_t)(row0 + quad*4 + r)*HH + col0 + t*16 + m] =
                    __float2bfloat16((acc[t][r] + bv[t]) * sc[r]);
    }
}

// LDS-staged SpMM: H0 = bf16(relu( dis_i * sum_{j in N(i)} Z'[j] + bias )).
// grid 192 = batch(16) x [slice(6) x half(2)]; block 512 thr. Z slice in LDS (64 KB).
// Fused stats (8-bucket) for layers 0,1; pool sums for layer 2.
__global__ __launch_bounds__(512) void spmm(const void* __restrict__ bias, int layer,
                                            float* __restrict__ stat_out, int is_pool,
                                            float* ws) {
    __shared__ unsigned int Zs[NN*16];   // exactly 64 KB
    const int isf = ((const int*)ws)[OFF_FLAG];
    int tid = threadIdx.x;
    int bi = blockIdx.x;
    int batch = bi & 15;
    int rest  = bi >> 4;          // 0..11
    int slice = rest % 6;         // channel slice: c0 = slice*32
    int half  = rest / 6;         // rows [half*512, half*512+512)
    int c0 = slice*32;
    const unsigned int* Zu = (const unsigned int*)(ws + OFF_ZB)
                             + (size_t)batch*NN*96 + c0/2;
    for (int i = tid; i < NN*16; i += 512) {
        int r = i >> 4, u = i & 15;
        Zs[i] = Zu[(size_t)r*96 + u];
    }
    __syncthreads();
    int d = tid & 7, rslot = tid >> 3;
    const float* dis = ws + OFF_DIS;
    const int* cnt = (const int*)(ws + OFF_CNT);
    const unsigned short* cols = (const unsigned short*)(ws + OFF_COLS);
    unsigned int* H0u = (unsigned int*)(ws + OFF_H0);
    float bch[4];
    #pragma unroll
    for (int e = 0; e < 4; ++e)
        bch[e] = ldin(bias, (size_t)layer*HH + c0 + d*4 + e, isf);
    float s_acc[4] = {0.f,0.f,0.f,0.f}, q_acc[4] = {0.f,0.f,0.f,0.f};
    for (int it = 0; it < 8; ++it) {
        int row = batch*NN + half*512 + it*64 + rslot;
        int c = cnt[row];
        const unsigned short* cl = cols + (size_t)row*MAXC;
        float a0=0.f, a1=0.f, a2=0.f, a3=0.f;
        int k = 0;
        for (; k + 8 <= c; k += 8) {
            u32x4 cw = *(const u32x4*)(cl + k);
            int j[8];
            j[0]=(int)(cw[0]&0xFFFFu); j[1]=(int)(cw[0]>>16);
            j[2]=(int)(cw[1]&0xFFFFu); j[3]=(int)(cw[1]>>16);
            j[4]=(int)(cw[2]&0xFFFFu); j[5]=(int)(cw[2]>>16);
            j[6]=(int)(cw[3]&0xFFFFu); j[7]=(int)(cw[3]>>16);
            u32x2 z[8];
            #pragma unroll
            for (int e = 0; e < 8; ++e)
                z[e] = *(const u32x2*)(&Zs[j[e]*16 + d*2]);
            #pragma unroll
            for (int e = 0; e < 8; ++e) {
                a0 += blo(z[e][0]); a1 += bhi(z[e][0]);
                a2 += blo(z[e][1]); a3 += bhi(z[e][1]);
            }
        }
        for (; k < c; ++k) {
            u32x2 z = *(const u32x2*)(&Zs[(int)cl[k]*16 + d*2]);
            a0 += blo(z[0]); a1 += bhi(z[0]);
            a2 += blo(z[1]); a3 += bhi(z[1]);
        }
        float dd = dis[row];
        float o0 = fmaxf(dd*a0 + bch[0], 0.f);
        float o1 = fmaxf(dd*a1 + bch[1], 0.f);
        float o2 = fmaxf(dd*a2 + bch[2], 0.f);
        float o3 = fmaxf(dd*a3 + bch[3], 0.f);
        u32x2 outw; outw[0] = packbf(o0,o1); outw[1] = packbf(o2,o3);
        *(u32x2*)(&H0u[(size_t)row*96 + c0/2 + d*2]) = outw;
        s_acc[0]+=o0; s_acc[1]+=o1; s_acc[2]+=o2; s_acc[3]+=o3;
        q_acc[0]+=o0*o0; q_acc[1]+=o1*o1; q_acc[2]+=o2*o2; q_acc[3]+=o3*o3;
    }
    // reduce over rslot within each wave (lanes differing in bits 3..5 share d)
    #pragma unroll
    for (int e = 0; e < 4; ++e) {
        #pragma unroll
        for (int mask = 8; mask < 64; mask <<= 1) {
            s_acc[e] += __shfl_xor(s_acc[e], mask, 64);
            q_acc[e] += __shfl_xor(q_acc[e], mask, 64);
        }
    }
    if ((tid & 63) < 8) {
        if (is_pool) {
            #pragma unroll
            for (int e = 0; e < 4; ++e)
                atomicAdd(&ws[OFF_G + (size_t)batch*HH + c0 + d*4 + e], s_acc[e]);
        } else {
            float* st = stat_out + (bi & 7)*512;
            #pragma unroll
            for (int e = 0; e < 4; ++e) {
                atomicAdd(&st[c0 + d*4 + e],       s_acc[e]);
                atomicAdd(&st[256 + c0 + d*4 + e], q_acc[e]);
            }
        }
    }
}

// BN -> relu(linear) -> BN -> classifier -> log_softmax. One block, 768 thr.
__global__ __launch_bounds__(768) void tail(
                     const void* __restrict__ fc_g,  const void* __restrict__ fc_b,
                     const void* __restrict__ lin_W, const void* __restrict__ lin_b,
                     const void* __restrict__ hid_g, const void* __restrict__ hid_b,
                     const void* __restrict__ cls_W, const void* __restrict__ cls_b,
                     void* __restrict__ out, const float* ws) {
    __shared__ float g1[BB][HH];
    __shared__ float g2[BB][HH];
    __shared__ __hip_bfloat16 Wl[HH*HH];
    __shared__ float logits[BB][10];
    __shared__ float lse[BB];
    int tid = threadIdx.x;
    const int isf = ((const int*)ws)[OFF_FLAG];
    const float* g = ws + OFF_G;   // sums over N; scale by 1/NN
    if (isf) {
        const float* Wp = (const float*)lin_W;
        for (int i = tid; i < HH*HH; i += 768) Wl[i] = __float2bfloat16(Wp[i]);
    } else {
        const __hip_bfloat16* Wp = (const __hip_bfloat16*)lin_W;
        for (int i = tid; i < HH*HH; i += 768) Wl[i] = Wp[i];
    }
    if (tid < HH) {
        float s = 0.f, sq = 0.f;
        for (int b = 0; b < BB; ++b) {
            float v = g[b*HH + tid] * (1.f/NN);
            s += v; sq += v*v;
        }
        float m = s*(1.f/BB), var = sq*(1.f/BB) - m*m;
        float a = ldin(fc_g, tid, isf) * rsqrtf(var + EPSV);
        float c = ldin(fc_b, tid, isf) - m*a;
        for (int b = 0; b < BB; ++b) g1[b][tid] = g[b*HH + tid]*(1.f/NN)*a + c;
    }
    __syncthreads();
    {
        int n = tid % HH, bg = tid / HH;
        float lb = ldin(lin_b, n, isf);
        float a0 = lb, a1 = lb, a2 = lb, a3 = lb;
        int b0 = bg*4;
        for (int k = 0; k < HH; ++k) {
            float wv = bf(Wl[k*HH + n]);
            a0 += g1[b0+0][k]*wv;
            a1 += g1[b0+1][k]*wv;
            a2 += g1[b0+2][k]*wv;
            a3 += g1[b0+3][k]*wv;
        }
        g2[b0+0][n] = fmaxf(a0, 0.f);
        g2[b0+1][n] = fmaxf(a1, 0.f);
        g2[b0+2][n] = fmaxf(a2, 0.f);
        g2[b0+3][n] = fmaxf(a3, 0.f);
    }
    __syncthreads();
    if (tid < HH) {
        float s = 0.f, sq = 0.f;
        for (int b = 0; b < BB; ++b) { float v = g2[b][tid]; s += v; sq += v*v; }
        float m = s*(1.f/BB), var = sq*(1.f/BB) - m*m;
        float a = ldin(hid_g, tid, isf) * rsqrtf(var + EPSV);
        float c = ldin(hid_b, tid, isf) - m*a;
        for (int b = 0; b < BB; ++b) g2[b][tid] = g2[b][tid]*a + c;
    }
    __syncthreads();
    if (tid < BB*10) {
        int b = tid/10, k = tid%10;
        float acc = ldin(cls_b, k, isf);
        for (int h = 0; h < HH; ++h) acc += g2[b][h] * ldin(cls_W, (size_t)h*10 + k, isf);
        logits[b][k] = acc;
    }
    __syncthreads();
    if (tid < BB) {
        float m = -1e30f;
        for (int k = 0; k < 10; ++k) m = fmaxf(m, logits[tid][k]);
        float s = 0.f;
        for (int k = 0; k < 10; ++k) s += expf(logits[tid][k] - m);
        lse[tid] = m + logf(s);
    }
    __syncthreads();
    if (tid < BB*10) {
        int b = tid/10;
        float v = logits[b][tid%10] - lse[b];
        if (isf) ((float*)out)[tid] = v;
        else     ((__hip_bfloat16*)out)[tid] = __float2bfloat16(v);
    }
}

extern "C" void kernel_launch(void* const* d_in, const int* in_sizes, int n_in,
                              void* d_out, int out_size, void* d_ws, size_t ws_size,
                              hipStream_t stream) {
    const void* x       = d_in[0];
    const void* adj     = d_in[1];
    const void* bnf_g   = d_in[2];
    const void* bnf_b   = d_in[3];
    const void* W_feat  = d_in[4];
    const void* bnc_g   = d_in[5];
    const void* bnc_b   = d_in[6];
    const void* convs_W = d_in[7];
    const void* convs_b = d_in[8];
    const void* fc_g    = d_in[9];
    const void* fc_b    = d_in[10];
    const void* lin_W   = d_in[11];
    const void* lin_b   = d_in[12];
    const void* hid_g   = d_in[13];
    const void* hid_b   = d_in[14];
    const void* cls_W   = d_in[15];
    const void* cls_b   = d_in[16];

    float* ws = (float*)d_ws;

    detect_and_zero<<<1, 256, 0, stream>>>((const unsigned int*)adj, ws);
    phase1<<<NROWS + 256, 256, 0, stream>>>(adj, x, ws);
    gemm_mfma<FF, 0><<<NROWS/32, 256, 0, stream>>>(x, W_feat, bnf_g, bnf_b, 0, ws);
    for (int l = 0; l < 3; ++l) {
        gemm_mfma<HH, 1><<<NROWS/32, 256, 0, stream>>>(
            (const void*)(ws + OFF_H0), convs_W, bnc_g, bnc_b, l, ws);
        spmm<<<192, 512, 0, stream>>>(convs_b, l,
            (l < 2) ? stage_h(ws, l + 1) : nullptr, (l == 2) ? 1 : 0, ws);
    }
    tail<<<1, 768, 0, stream>>>(fc_g, fc_b, lin_W, lin_b,
                                hid_g, hid_b, cls_W, cls_b, d_out, ws);
}

// Round 13
// 315.862 us; speedup vs baseline: 3.6826x; 1.3515x over previous
//
#include <hip/hip_runtime.h>
#include <hip/hip_bf16.h>

#define BB 16
#define NN 1024
#define FF 128
#define HH 192
#define NROWS (BB*NN)
#define MAXC 128
#define EPSV 1e-5f

// workspace layout, in float (4B) units (~18 MB total)
constexpr size_t OFF_H0  = 0;                                   // [NROWS*HH] bf16 (h, post-relu)
constexpr size_t OFF_ZB  = OFF_H0 + (size_t)NROWS*HH/2;         // [NROWS*HH] bf16 (Z')
constexpr size_t OFF_DIS = OFF_ZB + (size_t)NROWS*HH/2;         // [NROWS] f32
constexpr size_t OFF_G   = OFF_DIS + NROWS;                     // [BB*HH] f32 pool sums (atomics, zeroed by phase1)
constexpr size_t OFF_SH  = OFF_G + BB*HH;                       // 3 stages x 8 buckets x 512 (atomics, zeroed by phase1)
constexpr size_t SH_SIZE = 3*8*512;                             // 12288
constexpr size_t ZERO_SZ = BB*HH + SH_SIZE;                     // 15360 floats zeroed by phase1 blocks 0..59
constexpr size_t OFF_XB  = OFF_SH + SH_SIZE;                    // x-stat buckets [256][256] plain stores
constexpr size_t OFF_WPF = OFF_XB + 256*256;                    // [HH*FF] bf16 feat W'T
constexpr size_t OFF_WPC = OFF_WPF + (size_t)HH*FF/2;           // [HH*HH] bf16 conv W'T (per layer)
constexpr size_t OFF_BF  = OFF_WPC + (size_t)HH*HH/2;           // [HH] f32
constexpr size_t OFF_BC  = OFF_BF + HH;                         // [HH] f32
constexpr size_t OFF_CNT = OFF_BC + HH;                         // [NROWS] int32
constexpr size_t OFF_COLS= OFF_CNT + NROWS;                     // [NROWS*MAXC] u16

typedef __attribute__((ext_vector_type(8))) short short8;   // 8 bf16 in 4 VGPRs
typedef __attribute__((ext_vector_type(4))) float f32x4;
typedef __attribute__((ext_vector_type(4))) unsigned int u32x4;
typedef __attribute__((ext_vector_type(2))) unsigned int u32x2;

static __device__ __forceinline__ float bf(const __hip_bfloat16 v) {
    return __bfloat162float(v);
}
static __device__ __forceinline__ float ldin(const void* p, size_t i, int isf) {
    return isf ? ((const float*)p)[i]
               : __bfloat162float(((const __hip_bfloat16*)p)[i]);
}
static __host__ __device__ __forceinline__ float* stage_h(float* ws, int s /*0..2*/) {
    return ws + OFF_SH + (size_t)s*8*512;
}
static __device__ __forceinline__ float blo(unsigned int u) {
    union { unsigned int x; float f; } v; v.x = u << 16; return v.f;
}
static __device__ __forceinline__ float bhi(unsigned int u) {
    union { unsigned int x; float f; } v; v.x = u & 0xFFFF0000u; return v.f;
}
static __device__ __forceinline__ unsigned int packbf(float a, float b) {
    union { unsigned int u; __hip_bfloat16 h[2]; } p;
    p.h[0] = __float2bfloat16(a); p.h[1] = __float2bfloat16(b);
    return p.u;
}

// Per-block dtype self-detection: adj elements are exactly {0,1}. As f32 words
// the low 16 bits are never 0x3F80; as packed bf16, even-index 1.0 elements hit
// it (~20 expected in the first 1024 words). 4 KB scan, L2/L3-broadcast-hot.
// sh_flag: one int of LDS. Returns 1 => inputs are f32.
template<int NTHR>
static __device__ __forceinline__ int detect_isf(const unsigned int* __restrict__ adjw,
                                                 int tid, int* sh_flag) {
    if (tid == 0) *sh_flag = 0;
    __syncthreads();
    int hit = 0;
    #pragma unroll
    for (int k = tid; k < 1024; k += NTHR)
        if ((adjw[k] & 0xFFFFu) == 0x3F80u) hit = 1;
    if (hit) *sh_flag = 1;
    __syncthreads();
    return (*sh_flag == 0) ? 1 : 0;
}

// Role-split kernel:
//  blocks [0,NROWS): build graph row (+ first 60 blocks zero atomic stat/pool regions)
//  blocks [NROWS, NROWS+256): per-feature x-stats -> plain-store bucket [b2][256]
__global__ __launch_bounds__(256) void phase1(const void* __restrict__ adj,
                                              const void* __restrict__ x, float* ws) {
    __shared__ int sflag;
    int tid = threadIdx.x;
    const int isf = detect_isf<256>((const unsigned int*)adj, tid, &sflag);
    if (blockIdx.x < NROWS) {
        int row = blockIdx.x;
        // first 60 blocks zero the atomic accumulator regions (pool + stage_h);
        // consumed only after >=2 kernel boundaries.
        if (row < 60) {
            size_t idx = (size_t)row*256 + tid;
            if (idx < ZERO_SZ) ws[OFF_G + idx] = 0.f;
        }
        int i   = row & (NN - 1);
        __shared__ int cnt_s;
        __shared__ unsigned short colbuf[MAXC];
        if (tid == 0) cnt_s = 0;
        __syncthreads();
        int j0 = tid*4;
        unsigned int bits[4];
        if (isf) {
            u32x4 v = *(const u32x4*)((const unsigned int*)adj + (size_t)row*NN + j0);
            bits[0]=v[0]; bits[1]=v[1]; bits[2]=v[2]; bits[3]=v[3];
        } else {
            u32x2 v = *(const u32x2*)((const unsigned short*)adj + (size_t)row*NN + j0);
            bits[0]=(v[0]&0xFFFFu); bits[1]=(v[0]>>16); bits[2]=(v[1]&0xFFFFu); bits[3]=(v[1]>>16);
        }
        #pragma unroll
        for (int e = 0; e < 4; ++e) {
            int j = j0 + e;
            if ((bits[e] << 1) != 0u || j == i) {   // value != +-0  (or self loop)
                int p = atomicAdd(&cnt_s, 1);
                if (p < MAXC) colbuf[p] = (unsigned short)j;
            }
        }
        __syncthreads();
        int c = cnt_s; if (c > MAXC) c = MAXC;
        if (tid == 0) {
            ((int*)(ws + OFF_CNT))[row] = c;
            ws[OFF_DIS + row] = rsqrtf((float)cnt_s);   // deg >= 1 (self loop)
        }
        unsigned short* cols = (unsigned short*)(ws + OFF_COLS);
        for (int k = tid; k < c; k += 256) cols[(size_t)row*MAXC + k] = colbuf[k];
    } else {
        int b2 = blockIdx.x - NROWS;          // 0..255
        int f = tid & (FF-1), half = tid >> 7;
        int r0 = b2*64 + half*32;
        float s = 0.f, sq = 0.f;
        for (int r = 0; r < 32; ++r) {
            float v = ldin(x, (size_t)(r0 + r)*FF + f, isf);
            s += v; sq += v*v;
        }
        __shared__ float xs[256];
        if (half == 1) { xs[f] = s; xs[128 + f] = sq; }
        __syncthreads();
        if (half == 0) {
            ws[OFF_XB + (size_t)b2*256 + f]       = s  + xs[f];
            ws[OFF_XB + (size_t)b2*256 + 128 + f] = sq + xs[128 + f];
        }
    }
}

// BN-fold feat: W'T[n][k] = a_k W[k][n] (bf16), BF[n] = sum_k c_k W[k][n].
// grid HH blocks (n), FF threads (k). Sums the 256 plain-store x-buckets.
__global__ __launch_bounds__(128) void prep_feat(const void* __restrict__ adj,
                          const void* __restrict__ W_feat,
                          const void* __restrict__ gg, const void* __restrict__ bb,
                          float* ws) {
    __shared__ int sflag;
    int n = blockIdx.x, k = threadIdx.x;
    const int isf = detect_isf<128>((const unsigned int*)adj, k, &sflag);
    float s = 0.f, q = 0.f;
    for (int b = 0; b < 256; ++b) {
        s += ws[OFF_XB + (size_t)b*256 + k];
        q += ws[OFF_XB + (size_t)b*256 + 128 + k];
    }
    float m   = s * (1.f/NROWS);
    float var = q * (1.f/NROWS) - m*m;
    float a   = ldin(gg, k, isf) * rsqrtf(var + EPSV);
    float c   = ldin(bb, k, isf) - m*a;
    float wv  = ldin(W_feat, (size_t)k*HH + n, isf);
    ((__hip_bfloat16*)(ws + OFF_WPF))[(size_t)n*FF + k] = __float2bfloat16(a*wv);
    __shared__ float red[FF];
    red[k] = c*wv;
    __syncthreads();
    for (int s2 = FF/2; s2 > 0; s2 >>= 1) {
        if (k < s2) red[k] += red[k + s2];
        __syncthreads();
    }
    if (k == 0) ws[OFF_BF + n] = red[0];
}

// BN-fold conv layer l (reads 8-bucket atomic stats of stage l).
__global__ __launch_bounds__(192) void prep_conv(const void* __restrict__ adj,
                          const void* __restrict__ convs_W,
                          const void* __restrict__ gg, const void* __restrict__ bb,
                          int layer, float* ws) {
    __shared__ int sflag;
    int n = blockIdx.x, k = threadIdx.x;
    const int isf = detect_isf<192>((const unsigned int*)adj, k, &sflag);
    const float* st = stage_h(ws, layer);
    float s = 0.f, sq = 0.f;
    #pragma unroll
    for (int bkt = 0; bkt < 8; ++bkt) {
        s  += st[bkt*512 + k];
        sq += st[bkt*512 + 256 + k];
    }
    float m   = s * (1.f/NROWS);
    float var = sq * (1.f/NROWS) - m*m;
    float a   = ldin(gg, (size_t)layer*HH + k, isf) * rsqrtf(var + EPSV);
    float c   = ldin(bb, (size_t)layer*HH + k, isf) - m*a;
    float wv  = ldin(convs_W, (size_t)layer*HH*HH + (size_t)k*HH + n, isf);
    ((__hip_bfloat16*)(ws + OFF_WPC))[(size_t)n*HH + k] = __float2bfloat16(a*wv);
    __shared__ float red[HH];
    red[k] = c*wv;
    __syncthreads();
    if (k < 96) red[k] += red[k + 96];
    __syncthreads();
    for (int s2 = 48; s2 >= 3; s2 >>= 1) {
        if (k < s2) red[k] += red[k + s2];
        __syncthreads();
    }
    if (k == 0) ws[OFF_BC + n] = red[0] + red[1] + red[2];
}

// C = A[M x K] @ W'T[N x K]^T + bias via MFMA 16x16x32 bf16. B read from global
// (L2-hot). Block 256thr = 4 waves 2x2: wave = 16 rows x 96 cols. grid 512.
// XCD-locality swizzle: batch = blockIdx & 15.
// MODE 0 (feat): A=x (isf dtype), H0 = bf16(relu(C)); fused stage-0 stats.
// MODE 1 (conv): A=H0 bf16, Z' = bf16(dis[row]*C).
template<int K, int MODE>
__global__ __launch_bounds__(256) void gemm_mfma(const void* __restrict__ adj,
                                                 const void* __restrict__ A,
                                                 const __hip_bfloat16* __restrict__ BT,
                                                 const float* __restrict__ bias,
                                                 float* __restrict__ ws) {
    __shared__ int sflag;
    int tid = threadIdx.x;
    const int isf = detect_isf<256>((const unsigned int*)adj, tid, &sflag);
    int lane = tid & 63, w = tid >> 6;
    int wr = w & 1, wc = w >> 1;
    int bi = blockIdx.x;
    int batch = bi & 15, seg = bi >> 4;               // seg 0..31
    int row0 = batch*NN + seg*32 + wr*16;
    int col0 = wc*96;
    int m    = lane & 15, quad = lane >> 4;
    f32x4 acc[6];
    #pragma unroll
    for (int t = 0; t < 6; ++t) acc[t] = f32x4{0.f,0.f,0.f,0.f};
    float bv[6];
    #pragma unroll
    for (int t = 0; t < 6; ++t) bv[t] = bias[col0 + t*16 + m];
    #pragma unroll
    for (int kb = 0; kb < K/32; ++kb) {
        short8 a;
        if (MODE == 0 && isf) {
            const float* Ar = (const float*)A + (size_t)(row0+m)*K + kb*32 + quad*8;
            f32x4 v0 = *(const f32x4*)Ar;
            f32x4 v1 = *(const f32x4*)(Ar + 4);
            union { short8 s8; __hip_bfloat16 h[8]; } u;
            #pragma unroll
            for (int e = 0; e < 4; ++e) {
                u.h[e]   = __float2bfloat16(v0[e]);
                u.h[e+4] = __float2bfloat16(v1[e]);
            }
            a = u.s8;
        } else {
            a = *(const short8*)((const __hip_bfloat16*)A +
                                 (size_t)(row0+m)*K + kb*32 + quad*8);
        }
        #pragma unroll
        for (int t = 0; t < 6; ++t) {
            short8 b = *(const short8*)(BT + (size_t)(col0 + t*16+m)*K + kb*32 + quad*8);
            acc[t] = __builtin_amdgcn_mfma_f32_16x16x32_bf16(a, b, acc[t], 0, 0, 0);
        }
    }
    if (MODE == 0) {
        __shared__ float sh[2*HH];
        for (int i = tid; i < 2*HH; i += 256) sh[i] = 0.f;
        __syncthreads();
        __hip_bfloat16* H0 = (__hip_bfloat16*)(ws + OFF_H0);
        #pragma unroll
        for (int t = 0; t < 6; ++t) {
            int ch = col0 + t*16 + m;
            float s = 0.f, sq = 0.f;
            #pragma unroll
            for (int r = 0; r < 4; ++r) {
                float o = fmaxf(acc[t][r] + bv[t], 0.f);
                H0[(size_t)(row0 + quad*4 + r)*HH + ch] = __float2bfloat16(o);
                s += o; sq += o*o;
            }
            atomicAdd(&sh[ch], s);
            atomicAdd(&sh[HH + ch], sq);
        }
        __syncthreads();
        float* st = stage_h(ws, 0) + (size_t)(bi & 7)*512;
        if (tid < HH) {
            atomicAdd(&st[tid], sh[tid]);
            atomicAdd(&st[256 + tid], sh[HH + tid]);
        }
    } else {
        const float* dis = ws + OFF_DIS;
        __hip_bfloat16* Z = (__hip_bfloat16*)(ws + OFF_ZB);
        float sc[4];
        #pragma unroll
        for (int r = 0; r < 4; ++r) sc[r] = dis[row0 + quad*4 + r];
        #pragma unroll
        for (int t = 0; t < 6; ++t)
            #pragma unroll
            for (int r = 0; r < 4; ++r)
                Z[(size_t)(row0 + quad*4 + r)*HH + col0 + t*16 + m] =
                    __float2bfloat16((acc[t][r] + bv[t]) * sc[r]);
    }
}

// LDS-staged SpMM: H0 = bf16(relu( dis_i * sum_{j in N(i)} Z'[j] + bias )).
// grid 384 = batch(16) x [slice(6) x quarter(4)]; block 512 thr.
// Stages Z[batch][:, c0:c0+32] (64 KB) in LDS; each block does 256 rows.
// Fused stats (8-bucket) for layers 0,1; pool sums for layer 2.
__global__ __launch_bounds__(512) void spmm(const void* __restrict__ adj,
                                            const void* __restrict__ bias, int layer,
                                            float* __restrict__ stat_out, int is_pool,
                                            float* ws) {
    __shared__ unsigned int Zs[NN*16];   // exactly 64 KB
    __shared__ int sflag;
    int tid = threadIdx.x;
    const int isf = detect_isf<512>((const unsigned int*)adj, tid, &sflag);
    int bi = blockIdx.x;
    int batch = bi & 15;
    int rest  = bi >> 4;          // 0..23
    int slice = rest % 6;         // channel slice: c0 = slice*32
    int qtr   = rest / 6;         // rows [qtr*256, qtr*256+256)
    int c0 = slice*32;
    const unsigned int* Zu = (const unsigned int*)(ws + OFF_ZB)
                             + (size_t)batch*NN*96 + c0/2;
    for (int i = tid; i < NN*16; i += 512) {
        int r = i >> 4, u = i & 15;
        Zs[i] = Zu[(size_t)r*96 + u];
    }
    __syncthreads();
    int d = tid & 7, rslot = tid >> 3;
    const float* dis = ws + OFF_DIS;
    const int* cnt = (const int*)(ws + OFF_CNT);
    const unsigned short* cols = (const unsigned short*)(ws + OFF_COLS);
    unsigned int* H0u = (unsigned int*)(ws + OFF_H0);
    float bch[4];
    #pragma unroll
    for (int e = 0; e < 4; ++e)
        bch[e] = ldin(bias, (size_t)layer*HH + c0 + d*4 + e, isf);
    float s_acc[4] = {0.f,0.f,0.f,0.f}, q_acc[4] = {0.f,0.f,0.f,0.f};
    for (int it = 0; it < 4; ++it) {
        int row = batch*NN + qtr*256 + it*64 + rslot;
        int c = cnt[row];
        const unsigned short* cl = cols + (size_t)row*MAXC;
        float a0=0.f, a1=0.f, a2=0.f, a3=0.f;
        int k = 0;
        for (; k + 8 <= c; k += 8) {
            u32x4 cw = *(const u32x4*)(cl + k);
            int j[8];
            j[0]=(int)(cw[0]&0xFFFFu); j[1]=(int)(cw[0]>>16);
            j[2]=(int)(cw[1]&0xFFFFu); j[3]=(int)(cw[1]>>16);
            j[4]=(int)(cw[2]&0xFFFFu); j[5]=(int)(cw[2]>>16);
            j[6]=(int)(cw[3]&0xFFFFu); j[7]=(int)(cw[3]>>16);
            u32x2 z[8];
            #pragma unroll
            for (int e = 0; e < 8; ++e)
                z[e] = *(const u32x2*)(&Zs[j[e]*16 + d*2]);
            #pragma unroll
            for (int e = 0; e < 8; ++e) {
                a0 += blo(z[e][0]); a1 += bhi(z[e][0]);
                a2 += blo(z[e][1]); a3 += bhi(z[e][1]);
            }
        }
        for (; k < c; ++k) {
            u32x2 z = *(const u32x2*)(&Zs[(int)cl[k]*16 + d*2]);
            a0 += blo(z[0]); a1 += bhi(z[0]);
            a2 += blo(z[1]); a3 += bhi(z[1]);
        }
        float dd = dis[row];
        float o0 = fmaxf(dd*a0 + bch[0], 0.f);
        float o1 = fmaxf(dd*a1 + bch[1], 0.f);
        float o2 = fmaxf(dd*a2 + bch[2], 0.f);
        float o3 = fmaxf(dd*a3 + bch[3], 0.f);
        u32x2 outw; outw[0] = packbf(o0,o1); outw[1] = packbf(o2,o3);
        *(u32x2*)(&H0u[(size_t)row*96 + c0/2 + d*2]) = outw;
        s_acc[0]+=o0; s_acc[1]+=o1; s_acc[2]+=o2; s_acc[3]+=o3;
        q_acc[0]+=o0*o0; q_acc[1]+=o1*o1; q_acc[2]+=o2*o2; q_acc[3]+=o3*o3;
    }
    // reduce over rslot within each wave (lanes differing in bits 3..5 share d)
    #pragma unroll
    for (int e = 0; e < 4; ++e) {
        #pragma unroll
        for (int mask = 8; mask < 64; mask <<= 1) {
            s_acc[e] += __shfl_xor(s_acc[e], mask, 64);
            q_acc[e] += __shfl_xor(q_acc[e], mask, 64);
        }
    }
    if ((tid & 63) < 8) {
        if (is_pool) {
            #pragma unroll
            for (int e = 0; e < 4; ++e)
                atomicAdd(&ws[OFF_G + (size_t)batch*HH + c0 + d*4 + e], s_acc[e]);
        } else {
            float* st = stat_out + (bi & 7)*512;
            #pragma unroll
            for (int e = 0; e < 4; ++e) {
                atomicAdd(&st[c0 + d*4 + e],       s_acc[e]);
                atomicAdd(&st[256 + c0 + d*4 + e], q_acc[e]);
            }
        }
    }
}

// BN -> relu(linear) -> BN -> classifier -> log_softmax. One block, 768 thr.
__global__ __launch_bounds__(768) void tail(const void* __restrict__ adj,
                     const void* __restrict__ fc_g,  const void* __restrict__ fc_b,
                     const void* __restrict__ lin_W, const void* __restrict__ lin_b,
                     const void* __restrict__ hid_g, const void* __restrict__ hid_b,
                     const void* __restrict__ cls_W, const void* __restrict__ cls_b,
                     void* __restrict__ out, const float* ws) {
    __shared__ float g1[BB][HH];
    __shared__ float g2[BB][HH];
    __shared__ __hip_bfloat16 Wl[HH*HH];
    __shared__ float logits[BB][10];
    __shared__ float lse[BB];
    __shared__ int sflag;
    int tid = threadIdx.x;
    const int isf = detect_isf<768>((const unsigned int*)adj, tid, &sflag);
    const float* g = ws + OFF_G;   // sums over N; scale by 1/NN
    if (isf) {
        const float* Wp = (const float*)lin_W;
        for (int i = tid; i < HH*HH; i += 768) Wl[i] = __float2bfloat16(Wp[i]);
    } else {
        const __hip_bfloat16* Wp = (const __hip_bfloat16*)lin_W;
        for (int i = tid; i < HH*HH; i += 768) Wl[i] = Wp[i];
    }
    if (tid < HH) {
        float s = 0.f, sq = 0.f;
        for (int b = 0; b < BB; ++b) {
            float v = g[b*HH + tid] * (1.f/NN);
            s += v; sq += v*v;
        }
        float m = s*(1.f/BB), var = sq*(1.f/BB) - m*m;
        float a = ldin(fc_g, tid, isf) * rsqrtf(var + EPSV);
        float c = ldin(fc_b, tid, isf) - m*a;
        for (int b = 0; b < BB; ++b) g1[b][tid] = g[b*HH + tid]*(1.f/NN)*a + c;
    }
    __syncthreads();
    {
        int n = tid % HH, bg = tid / HH;
        float lb = ldin(lin_b, n, isf);
        float a0 = lb, a1 = lb, a2 = lb, a3 = lb;
        int b0 = bg*4;
        for (int k = 0; k < HH; ++k) {
            float wv = bf(Wl[k*HH + n]);
            a0 += g1[b0+0][k]*wv;
            a1 += g1[b0+1][k]*wv;
            a2 += g1[b0+2][k]*wv;
            a3 += g1[b0+3][k]*wv;
        }
        g2[b0+0][n] = fmaxf(a0, 0.f);
        g2[b0+1][n] = fmaxf(a1, 0.f);
        g2[b0+2][n] = fmaxf(a2, 0.f);
        g2[b0+3][n] = fmaxf(a3, 0.f);
    }
    __syncthreads();
    if (tid < HH) {
        float s = 0.f, sq = 0.f;
        for (int b = 0; b < BB; ++b) { float v = g2[b][tid]; s += v; sq += v*v; }
        float m = s*(1.f/BB), var = sq*(1.f/BB) - m*m;
        float a = ldin(hid_g, tid, isf) * rsqrtf(var + EPSV);
        float c = ldin(hid_b, tid, isf) - m*a;
        for (int b = 0; b < BB; ++b) g2[b][tid] = g2[b][tid]*a + c;
    }
    __syncthreads();
    if (tid < BB*10) {
        int b = tid/10, k = tid%10;
        float acc = ldin(cls_b, k, isf);
        for (int h = 0; h < HH; ++h) acc += g2[b][h] * ldin(cls_W, (size_t)h*10 + k, isf);
        logits[b][k] = acc;
    }
    __syncthreads();
    if (tid < BB) {
        float m = -1e30f;
        for (int k = 0; k < 10; ++k) m = fmaxf(m, logits[tid][k]);
        float s = 0.f;
        for (int k = 0; k < 10; ++k) s += expf(logits[tid][k] - m);
        lse[tid] = m + logf(s);
    }
    __syncthreads();
    if (tid < BB*10) {
        int b = tid/10;
        float v = logits[b][tid%10] - lse[b];
        if (isf) ((float*)out)[tid] = v;
        else     ((__hip_bfloat16*)out)[tid] = __float2bfloat16(v);
    }
}

extern "C" void kernel_launch(void* const* d_in, const int* in_sizes, int n_in,
                              void* d_out, int out_size, void* d_ws, size_t ws_size,
                              hipStream_t stream) {
    const void* x       = d_in[0];
    const void* adj     = d_in[1];
    const void* bnf_g   = d_in[2];
    const void* bnf_b   = d_in[3];
    const void* W_feat  = d_in[4];
    const void* bnc_g   = d_in[5];
    const void* bnc_b   = d_in[6];
    const void* convs_W = d_in[7];
    const void* convs_b = d_in[8];
    const void* fc_g    = d_in[9];
    const void* fc_b    = d_in[10];
    const void* lin_W   = d_in[11];
    const void* lin_b   = d_in[12];
    const void* hid_g   = d_in[13];
    const void* hid_b   = d_in[14];
    const void* cls_W   = d_in[15];
    const void* cls_b   = d_in[16];

    float* ws = (float*)d_ws;
    const __hip_bfloat16* WPF = (const __hip_bfloat16*)(ws + OFF_WPF);
    const __hip_bfloat16* WPC = (const __hip_bfloat16*)(ws + OFF_WPC);

    phase1<<<NROWS + 256, 256, 0, stream>>>(adj, x, ws);
    prep_feat<<<HH, FF, 0, stream>>>(adj, W_feat, bnf_g, bnf_b, ws);
    gemm_mfma<FF, 0><<<NROWS/32, 256, 0, stream>>>(adj, x, WPF, ws + OFF_BF, ws);
    for (int l = 0; l < 3; ++l) {
        prep_conv<<<HH, HH, 0, stream>>>(adj, convs_W, bnc_g, bnc_b, l, ws);
        gemm_mfma<HH, 1><<<NROWS/32, 256, 0, stream>>>(
            adj, (const void*)(ws + OFF_H0), WPC, ws + OFF_BC, ws);
        spmm<<<384, 512, 0, stream>>>(adj, convs_b, l,
            (l < 2) ? stage_h(ws, l + 1) : nullptr, (l == 2) ? 1 : 0, ws);
    }
    tail<<<1, 768, 0, stream>>>(adj, fc_g, fc_b, lin_W, lin_b,
                                hid_g, hid_b, cls_W, cls_b, d_out, ws);
}

// Round 14
// 311.299 us; speedup vs baseline: 3.7366x; 1.0147x over previous
//
#include <hip/hip_runtime.h>
#include <hip/hip_bf16.h>

#define BB 16
#define NN 1024
#define FF 128
#define HH 192
#define NROWS (BB*NN)
#define MAXC 128
#define EPSV 1e-5f

// workspace layout, in float (4B) units (~18 MB total)
constexpr size_t OFF_H0  = 0;                                   // [NROWS*HH] bf16 (h, post-relu)
constexpr size_t OFF_ZB  = OFF_H0 + (size_t)NROWS*HH/2;         // [NROWS*HH] bf16 (Z')
constexpr size_t OFF_DIS = OFF_ZB + (size_t)NROWS*HH/2;         // [NROWS] f32
constexpr size_t OFF_G   = OFF_DIS + NROWS;                     // [BB*HH] f32 pool sums (atomics, zeroed by phase1)
constexpr size_t OFF_SH  = OFF_G + BB*HH;                       // 3 stages x 8 buckets x 512 (atomics, zeroed by phase1)
constexpr size_t SH_SIZE = 3*8*512;                             // 12288
constexpr size_t ZERO_SZ = BB*HH + SH_SIZE;                     // 15360 floats zeroed by phase1 blocks 0..59
constexpr size_t OFF_XB  = OFF_SH + SH_SIZE;                    // x-stat buckets [256][256] plain stores
constexpr size_t OFF_WPF = OFF_XB + 256*256;                    // [HH*FF] bf16 feat W'T
constexpr size_t OFF_WPC = OFF_WPF + (size_t)HH*FF/2;           // [HH*HH] bf16 conv W'T (per layer)
constexpr size_t OFF_BF  = OFF_WPC + (size_t)HH*HH/2;           // [HH] f32
constexpr size_t OFF_BC  = OFF_BF + HH;                         // [HH] f32
constexpr size_t OFF_CNT = OFF_BC + HH;                         // [NROWS] int32
constexpr size_t OFF_COLS= OFF_CNT + NROWS;                     // [NROWS*MAXC] u16

typedef __attribute__((ext_vector_type(8))) short short8;   // 8 bf16 in 4 VGPRs
typedef __attribute__((ext_vector_type(4))) float f32x4;
typedef __attribute__((ext_vector_type(4))) unsigned int u32x4;
typedef __attribute__((ext_vector_type(2))) unsigned int u32x2;

static __device__ __forceinline__ float bf(const __hip_bfloat16 v) {
    return __bfloat162float(v);
}
static __device__ __forceinline__ float ldin(const void* p, size_t i, int isf) {
    return isf ? ((const float*)p)[i]
               : __bfloat162float(((const __hip_bfloat16*)p)[i]);
}
static __host__ __device__ __forceinline__ float* stage_h(float* ws, int s /*0..2*/) {
    return ws + OFF_SH + (size_t)s*8*512;
}
static __device__ __forceinline__ float blo(unsigned int u) {
    union { unsigned int x; float f; } v; v.x = u << 16; return v.f;
}
static __device__ __forceinline__ float bhi(unsigned int u) {
    union { unsigned int x; float f; } v; v.x = u & 0xFFFF0000u; return v.f;
}
static __device__ __forceinline__ unsigned int packbf(float a, float b) {
    union { unsigned int u; __hip_bfloat16 h[2]; } p;
    p.h[0] = __float2bfloat16(a); p.h[1] = __float2bfloat16(b);
    return p.u;
}

// Per-block dtype self-detection: adj elements are exactly {0,1}. As f32 words
// the low 16 bits are never 0x3F80; as packed bf16, even-index 1.0 elements hit
// it (~20 expected in the first 1024 words). 4 KB scan, L2/L3-broadcast-hot.
template<int NTHR>
static __device__ __forceinline__ int detect_isf(const unsigned int* __restrict__ adjw,
                                                 int tid, int* sh_flag) {
    if (tid == 0) *sh_flag = 0;
    __syncthreads();
    int hit = 0;
    #pragma unroll
    for (int k = tid; k < 1024; k += NTHR)
        if ((adjw[k] & 0xFFFFu) == 0x3F80u) hit = 1;
    if (hit) *sh_flag = 1;
    __syncthreads();
    return (*sh_flag == 0) ? 1 : 0;
}

// Role-split kernel:
//  blocks [0,NROWS): build graph row (+ first 60 blocks zero atomic stat/pool regions)
//  blocks [NROWS, NROWS+256): per-feature x-stats -> plain-store bucket [b2][256]
__global__ __launch_bounds__(256) void phase1(const void* __restrict__ adj,
                                              const void* __restrict__ x, float* ws) {
    __shared__ int sflag;
    int tid = threadIdx.x;
    const int isf = detect_isf<256>((const unsigned int*)adj, tid, &sflag);
    if (blockIdx.x < NROWS) {
        int row = blockIdx.x;
        if (row < 60) {
            size_t idx = (size_t)row*256 + tid;
            if (idx < ZERO_SZ) ws[OFF_G + idx] = 0.f;
        }
        int i   = row & (NN - 1);
        __shared__ int cnt_s;
        __shared__ unsigned short colbuf[MAXC];
        if (tid == 0) cnt_s = 0;
        __syncthreads();
        int j0 = tid*4;
        unsigned int bits[4];
        if (isf) {
            u32x4 v = *(const u32x4*)((const unsigned int*)adj + (size_t)row*NN + j0);
            bits[0]=v[0]; bits[1]=v[1]; bits[2]=v[2]; bits[3]=v[3];
        } else {
            u32x2 v = *(const u32x2*)((const unsigned short*)adj + (size_t)row*NN + j0);
            bits[0]=(v[0]&0xFFFFu); bits[1]=(v[0]>>16); bits[2]=(v[1]&0xFFFFu); bits[3]=(v[1]>>16);
        }
        #pragma unroll
        for (int e = 0; e < 4; ++e) {
            int j = j0 + e;
            if ((bits[e] << 1) != 0u || j == i) {   // value != +-0  (or self loop)
                int p = atomicAdd(&cnt_s, 1);
                if (p < MAXC) colbuf[p] = (unsigned short)j;
            }
        }
        __syncthreads();
        int c = cnt_s; if (c > MAXC) c = MAXC;
        if (tid == 0) {
            ((int*)(ws + OFF_CNT))[row] = c;
            ws[OFF_DIS + row] = rsqrtf((float)cnt_s);   // deg >= 1 (self loop)
        }
        unsigned short* cols = (unsigned short*)(ws + OFF_COLS);
        for (int k = tid; k < c; k += 256) cols[(size_t)row*MAXC + k] = colbuf[k];
    } else {
        int b2 = blockIdx.x - NROWS;          // 0..255
        int f = tid & (FF-1), half = tid >> 7;
        int r0 = b2*64 + half*32;
        float s = 0.f, sq = 0.f;
        for (int r = 0; r < 32; ++r) {
            float v = ldin(x, (size_t)(r0 + r)*FF + f, isf);
            s += v; sq += v*v;
        }
        __shared__ float xs[256];
        if (half == 1) { xs[f] = s; xs[128 + f] = sq; }
        __syncthreads();
        if (half == 0) {
            ws[OFF_XB + (size_t)b2*256 + f]       = s  + xs[f];
            ws[OFF_XB + (size_t)b2*256 + 128 + f] = sq + xs[128 + f];
        }
    }
}

// BN-fold feat: W'T[n][k] = a_k W[k][n] (bf16), BF[n] = sum_k c_k W[k][n].
__global__ __launch_bounds__(128) void prep_feat(const void* __restrict__ adj,
                          const void* __restrict__ W_feat,
                          const void* __restrict__ gg, const void* __restrict__ bb,
                          float* ws) {
    __shared__ int sflag;
    int n = blockIdx.x, k = threadIdx.x;
    const int isf = detect_isf<128>((const unsigned int*)adj, k, &sflag);
    float s = 0.f, q = 0.f;
    for (int b = 0; b < 256; ++b) {
        s += ws[OFF_XB + (size_t)b*256 + k];
        q += ws[OFF_XB + (size_t)b*256 + 128 + k];
    }
    float m   = s * (1.f/NROWS);
    float var = q * (1.f/NROWS) - m*m;
    float a   = ldin(gg, k, isf) * rsqrtf(var + EPSV);
    float c   = ldin(bb, k, isf) - m*a;
    float wv  = ldin(W_feat, (size_t)k*HH + n, isf);
    ((__hip_bfloat16*)(ws + OFF_WPF))[(size_t)n*FF + k] = __float2bfloat16(a*wv);
    __shared__ float red[FF];
    red[k] = c*wv;
    __syncthreads();
    for (int s2 = FF/2; s2 > 0; s2 >>= 1) {
        if (k < s2) red[k] += red[k + s2];
        __syncthreads();
    }
    if (k == 0) ws[OFF_BF + n] = red[0];
}

// BN-fold conv layer l (reads 8-bucket atomic stats of stage l).
__global__ __launch_bounds__(192) void prep_conv(const void* __restrict__ adj,
                          const void* __restrict__ convs_W,
                          const void* __restrict__ gg, const void* __restrict__ bb,
                          int layer, float* ws) {
    __shared__ int sflag;
    int n = blockIdx.x, k = threadIdx.x;
    const int isf = detect_isf<192>((const unsigned int*)adj, k, &sflag);
    const float* st = stage_h(ws, layer);
    float s = 0.f, sq = 0.f;
    #pragma unroll
    for (int bkt = 0; bkt < 8; ++bkt) {
        s  += st[bkt*512 + k];
        sq += st[bkt*512 + 256 + k];
    }
    float m   = s * (1.f/NROWS);
    float var = sq * (1.f/NROWS) - m*m;
    float a   = ldin(gg, (size_t)layer*HH + k, isf) * rsqrtf(var + EPSV);
    float c   = ldin(bb, (size_t)layer*HH + k, isf) - m*a;
    float wv  = ldin(convs_W, (size_t)layer*HH*HH + (size_t)k*HH + n, isf);
    ((__hip_bfloat16*)(ws + OFF_WPC))[(size_t)n*HH + k] = __float2bfloat16(a*wv);
    __shared__ float red[HH];
    red[k] = c*wv;
    __syncthreads();
    if (k < 96) red[k] += red[k + 96];
    __syncthreads();
    for (int s2 = 48; s2 >= 3; s2 >>= 1) {
        if (k < s2) red[k] += red[k + s2];
        __syncthreads();
    }
    if (k == 0) ws[OFF_BC + n] = red[0] + red[1] + red[2];
}

// C = A[M x K] @ W'T[N x K]^T + bias via MFMA 16x16x32 bf16. B read from global
// (L2-hot). Block 256thr = 4 waves 2x2: wave = 16 rows x 96 cols. grid 512.
// XCD-locality swizzle: batch = blockIdx & 15.
template<int K, int MODE>
__global__ __launch_bounds__(256) void gemm_mfma(const void* __restrict__ adj,
                                                 const void* __restrict__ A,
                                                 const __hip_bfloat16* __restrict__ BT,
                                                 const float* __restrict__ bias,
                                                 float* __restrict__ ws) {
    __shared__ int sflag;
    int tid = threadIdx.x;
    const int isf = detect_isf<256>((const unsigned int*)adj, tid, &sflag);
    int lane = tid & 63, w = tid >> 6;
    int wr = w & 1, wc = w >> 1;
    int bi = blockIdx.x;
    int batch = bi & 15, seg = bi >> 4;               // seg 0..31
    int row0 = batch*NN + seg*32 + wr*16;
    int col0 = wc*96;
    int m    = lane & 15, quad = lane >> 4;
    f32x4 acc[6];
    #pragma unroll
    for (int t = 0; t < 6; ++t) acc[t] = f32x4{0.f,0.f,0.f,0.f};
    float bv[6];
    #pragma unroll
    for (int t = 0; t < 6; ++t) bv[t] = bias[col0 + t*16 + m];
    #pragma unroll
    for (int kb = 0; kb < K/32; ++kb) {
        short8 a;
        if (MODE == 0 && isf) {
            const float* Ar = (const float*)A + (size_t)(row0+m)*K + kb*32 + quad*8;
            f32x4 v0 = *(const f32x4*)Ar;
            f32x4 v1 = *(const f32x4*)(Ar + 4);
            union { short8 s8; __hip_bfloat16 h[8]; } u;
            #pragma unroll
            for (int e = 0; e < 4; ++e) {
                u.h[e]   = __float2bfloat16(v0[e]);
                u.h[e+4] = __float2bfloat16(v1[e]);
            }
            a = u.s8;
        } else {
            a = *(const short8*)((const __hip_bfloat16*)A +
                                 (size_t)(row0+m)*K + kb*32 + quad*8);
        }
        #pragma unroll
        for (int t = 0; t < 6; ++t) {
            short8 b = *(const short8*)(BT + (size_t)(col0 + t*16+m)*K + kb*32 + quad*8);
            acc[t] = __builtin_amdgcn_mfma_f32_16x16x32_bf16(a, b, acc[t], 0, 0, 0);
        }
    }
    if (MODE == 0) {
        __shared__ float sh[2*HH];
        for (int i = tid; i < 2*HH; i += 256) sh[i] = 0.f;
        __syncthreads();
        __hip_bfloat16* H0 = (__hip_bfloat16*)(ws + OFF_H0);
        #pragma unroll
        for (int t = 0; t < 6; ++t) {
            int ch = col0 + t*16 + m;
            float s = 0.f, sq = 0.f;
            #pragma unroll
            for (int r = 0; r < 4; ++r) {
                float o = fmaxf(acc[t][r] + bv[t], 0.f);
                H0[(size_t)(row0 + quad*4 + r)*HH + ch] = __float2bfloat16(o);
                s += o; sq += o*o;
            }
            atomicAdd(&sh[ch], s);
            atomicAdd(&sh[HH + ch], sq);
        }
        __syncthreads();
        float* st = stage_h(ws, 0) + (size_t)(bi & 7)*512;
        if (tid < HH) {
            atomicAdd(&st[tid], sh[tid]);
            atomicAdd(&st[256 + tid], sh[HH + tid]);
        }
    } else {
        const float* dis = ws + OFF_DIS;
        __hip_bfloat16* Z = (__hip_bfloat16*)(ws + OFF_ZB);
        float sc[4];
        #pragma unroll
        for (int r = 0; r < 4; ++r) sc[r] = dis[row0 + quad*4 + r];
        #pragma unroll
        for (int t = 0; t < 6; ++t)
            #pragma unroll
            for (int r = 0; r < 4; ++r)
                Z[(size_t)(row0 + quad*4 + r)*HH + col0 + t*16 + m] =
                    __float2bfloat16((acc[t][r] + bv[t]) * sc[r]);
    }
}

// LDS-staged SpMM: H0 = bf16(relu( dis_i * sum_{j in N(i)} Z'[j] + bias )).
// grid 384 = batch(16) x [slice(6) x quarter(4)]; block 512 thr.
__global__ __launch_bounds__(512) void spmm(const void* __restrict__ adj,
                                            const void* __restrict__ bias, int layer,
                                            float* __restrict__ stat_out, int is_pool,
                                            float* ws) {
    __shared__ unsigned int Zs[NN*16];   // exactly 64 KB
    __shared__ int sflag;
    int tid = threadIdx.x;
    const int isf = detect_isf<512>((const unsigned int*)adj, tid, &sflag);
    int bi = blockIdx.x;
    int batch = bi & 15;
    int rest  = bi >> 4;          // 0..23
    int slice = rest % 6;         // channel slice: c0 = slice*32
    int qtr   = rest / 6;         // rows [qtr*256, qtr*256+256)
    int c0 = slice*32;
    const unsigned int* Zu = (const unsigned int*)(ws + OFF_ZB)
                             + (size_t)batch*NN*96 + c0/2;
    for (int i = tid; i < NN*16; i += 512) {
        int r = i >> 4, u = i & 15;
        Zs[i] = Zu[(size_t)r*96 + u];
    }
    __syncthreads();
    int d = tid & 7, rslot = tid >> 3;
    const float* dis = ws + OFF_DIS;
    const int* cnt = (const int*)(ws + OFF_CNT);
    const unsigned short* cols = (const unsigned short*)(ws + OFF_COLS);
    unsigned int* H0u = (unsigned int*)(ws + OFF_H0);
    float bch[4];
    #pragma unroll
    for (int e = 0; e < 4; ++e)
        bch[e] = ldin(bias, (size_t)layer*HH + c0 + d*4 + e, isf);
    float s_acc[4] = {0.f,0.f,0.f,0.f}, q_acc[4] = {0.f,0.f,0.f,0.f};
    for (int it = 0; it < 4; ++it) {
        int row = batch*NN + qtr*256 + it*64 + rslot;
        int c = cnt[row];
        const unsigned short* cl = cols + (size_t)row*MAXC;
        float a0=0.f, a1=0.f, a2=0.f, a3=0.f;
        int k = 0;
        for (; k + 8 <= c; k += 8) {
            u32x4 cw = *(const u32x4*)(cl + k);
            int j[8];
            j[0]=(int)(cw[0]&0xFFFFu); j[1]=(int)(cw[0]>>16);
            j[2]=(int)(cw[1]&0xFFFFu); j[3]=(int)(cw[1]>>16);
            j[4]=(int)(cw[2]&0xFFFFu); j[5]=(int)(cw[2]>>16);
            j[6]=(int)(cw[3]&0xFFFFu); j[7]=(int)(cw[3]>>16);
            u32x2 z[8];
            #pragma unroll
            for (int e = 0; e < 8; ++e)
                z[e] = *(const u32x2*)(&Zs[j[e]*16 + d*2]);
            #pragma unroll
            for (int e = 0; e < 8; ++e) {
                a0 += blo(z[e][0]); a1 += bhi(z[e][0]);
                a2 += blo(z[e][1]); a3 += bhi(z[e][1]);
            }
        }
        for (; k < c; ++k) {
            u32x2 z = *(const u32x2*)(&Zs[(int)cl[k]*16 + d*2]);
            a0 += blo(z[0]); a1 += bhi(z[0]);
            a2 += blo(z[1]); a3 += bhi(z[1]);
        }
        float dd = dis[row];
        float o0 = fmaxf(dd*a0 + bch[0], 0.f);
        float o1 = fmaxf(dd*a1 + bch[1], 0.f);
        float o2 = fmaxf(dd*a2 + bch[2], 0.f);
        float o3 = fmaxf(dd*a3 + bch[3], 0.f);
        u32x2 outw; outw[0] = packbf(o0,o1); outw[1] = packbf(o2,o3);
        *(u32x2*)(&H0u[(size_t)row*96 + c0/2 + d*2]) = outw;
        s_acc[0]+=o0; s_acc[1]+=o1; s_acc[2]+=o2; s_acc[3]+=o3;
        q_acc[0]+=o0*o0; q_acc[1]+=o1*o1; q_acc[2]+=o2*o2; q_acc[3]+=o3*o3;
    }
    #pragma unroll
    for (int e = 0; e < 4; ++e) {
        #pragma unroll
        for (int mask = 8; mask < 64; mask <<= 1) {
            s_acc[e] += __shfl_xor(s_acc[e], mask, 64);
            q_acc[e] += __shfl_xor(q_acc[e], mask, 64);
        }
    }
    if ((tid & 63) < 8) {
        if (is_pool) {
            #pragma unroll
            for (int e = 0; e < 4; ++e)
                atomicAdd(&ws[OFF_G + (size_t)batch*HH + c0 + d*4 + e], s_acc[e]);
        } else {
            float* st = stat_out + (bi & 7)*512;
            #pragma unroll
            for (int e = 0; e < 4; ++e) {
                atomicAdd(&st[c0 + d*4 + e],       s_acc[e]);
                atomicAdd(&st[256 + c0 + d*4 + e], q_acc[e]);
            }
        }
    }
}

// BN -> relu(linear) -> BN -> classifier -> log_softmax. One block, 768 thr.
// lin_W staged via 16B vector loads; linear phase = (batch, 4-col) mapping:
// g1[b][k] is a wave-broadcast LDS read, Wl[k][n0..n0+3] an 8B vector read.
__global__ __launch_bounds__(768) void tail(const void* __restrict__ adj,
                     const void* __restrict__ fc_g,  const void* __restrict__ fc_b,
                     const void* __restrict__ lin_W, const void* __restrict__ lin_b,
                     const void* __restrict__ hid_g, const void* __restrict__ hid_b,
                     const void* __restrict__ cls_W, const void* __restrict__ cls_b,
                     void* __restrict__ out, const float* ws) {
    __shared__ float g1[BB][HH];
    __shared__ float g2[BB][HH];
    __shared__ __hip_bfloat16 Wl[HH*HH];
    __shared__ float logits[BB][10];
    __shared__ float lse[BB];
    __shared__ int sflag;
    int tid = threadIdx.x;
    const int isf = detect_isf<768>((const unsigned int*)adj, tid, &sflag);
    const float* g = ws + OFF_G;   // sums over N; scale by 1/NN
    // ---- stage lin_W -> LDS with 16B loads ----
    if (isf) {
        const f32x4* Wp = (const f32x4*)lin_W;
        for (int i = tid; i < HH*HH/8; i += 768) {
            f32x4 v0 = Wp[2*i], v1 = Wp[2*i + 1];
            union { short8 s8; __hip_bfloat16 h[8]; } u;
            #pragma unroll
            for (int e = 0; e < 4; ++e) {
                u.h[e]   = __float2bfloat16(v0[e]);
                u.h[e+4] = __float2bfloat16(v1[e]);
            }
            *(short8*)&Wl[8*i] = u.s8;
        }
    } else {
        const short8* Wp = (const short8*)lin_W;
        for (int i = tid; i < HH*HH/8; i += 768)
            *(short8*)&Wl[8*i] = Wp[i];
    }
    if (tid < HH) {
        float s = 0.f, sq = 0.f;
        for (int b = 0; b < BB; ++b) {
            float v = g[b*HH + tid] * (1.f/NN);
            s += v; sq += v*v;
        }
        float m = s*(1.f/BB), var = sq*(1.f/BB) - m*m;
        float a = ldin(fc_g, tid, isf) * rsqrtf(var + EPSV);
        float c = ldin(fc_b, tid, isf) - m*a;
        for (int b = 0; b < BB; ++b) g1[b][tid] = g[b*HH + tid]*(1.f/NN)*a + c;
    }
    __syncthreads();
    // ---- linear: 768 = 16 batches x 48 col-groups (4 cols each) ----
    {
        int b = tid / 48, grp = tid - b*48;
        int n0 = grp*4;
        float acc[4];
        #pragma unroll
        for (int e = 0; e < 4; ++e) acc[e] = ldin(lin_b, n0 + e, isf);
        for (int k = 0; k < HH; ++k) {
            float gv = g1[b][k];
            u32x2 wz = *(const u32x2*)&Wl[k*HH + n0];
            acc[0] += gv * blo(wz[0]); acc[1] += gv * bhi(wz[0]);
            acc[2] += gv * blo(wz[1]); acc[3] += gv * bhi(wz[1]);
        }
        #pragma unroll
        for (int e = 0; e < 4; ++e) g2[b][n0 + e] = fmaxf(acc[e], 0.f);
    }
    __syncthreads();
    if (tid < HH) {
        float s = 0.f, sq = 0.f;
        for (int b = 0; b < BB; ++b) { float v = g2[b][tid]; s += v; sq += v*v; }
        float m = s*(1.f/BB), var = sq*(1.f/BB) - m*m;
        float a = ldin(hid_g, tid, isf) * rsqrtf(var + EPSV);
        float c = ldin(hid_b, tid, isf) - m*a;
        for (int b = 0; b < BB; ++b) g2[b][tid] = g2[b][tid]*a + c;
    }
    __syncthreads();
    if (tid < BB*10) {
        int b = tid/10, k = tid%10;
        float acc = ldin(cls_b, k, isf);
        for (int h = 0; h < HH; ++h) acc += g2[b][h] * ldin(cls_W, (size_t)h*10 + k, isf);
        logits[b][k] = acc;
    }
    __syncthreads();
    if (tid < BB) {
        float m = -1e30f;
        for (int k = 0; k < 10; ++k) m = fmaxf(m, logits[tid][k]);
        float s = 0.f;
        for (int k = 0; k < 10; ++k) s += expf(logits[tid][k] - m);
        lse[tid] = m + logf(s);
    }
    __syncthreads();
    if (tid < BB*10) {
        int b = tid/10;
        float v = logits[b][tid%10] - lse[b];
        if (isf) ((float*)out)[tid] = v;
        else     ((__hip_bfloat16*)out)[tid] = __float2bfloat16(v);
    }
}

extern "C" void kernel_launch(void* const* d_in, const int* in_sizes, int n_in,
                              void* d_out, int out_size, void* d_ws, size_t ws_size,
                              hipStream_t stream) {
    const void* x       = d_in[0];
    const void* adj     = d_in[1];
    const void* bnf_g   = d_in[2];
    const void* bnf_b   = d_in[3];
    const void* W_feat  = d_in[4];
    const void* bnc_g   = d_in[5];
    const void* bnc_b   = d_in[6];
    const void* convs_W = d_in[7];
    const void* convs_b = d_in[8];
    const void* fc_g    = d_in[9];
    const void* fc_b    = d_in[10];
    const void* lin_W   = d_in[11];
    const void* lin_b   = d_in[12];
    const void* hid_g   = d_in[13];
    const void* hid_b   = d_in[14];
    const void* cls_W   = d_in[15];
    const void* cls_b   = d_in[16];

    float* ws = (float*)d_ws;
    const __hip_bfloat16* WPF = (const __hip_bfloat16*)(ws + OFF_WPF);
    const __hip_bfloat16* WPC = (const __hip_bfloat16*)(ws + OFF_WPC);

    phase1<<<NROWS + 256, 256, 0, stream>>>(adj, x, ws);
    prep_feat<<<HH, FF, 0, stream>>>(adj, W_feat, bnf_g, bnf_b, ws);
    gemm_mfma<FF, 0><<<NROWS/32, 256, 0, stream>>>(adj, x, WPF, ws + OFF_BF, ws);
    for (int l = 0; l < 3; ++l) {
        prep_conv<<<HH, HH, 0, stream>>>(adj, convs_W, bnc_g, bnc_b, l, ws);
        gemm_mfma<HH, 1><<<NROWS/32, 256, 0, stream>>>(
            adj, (const void*)(ws + OFF_H0), WPC, ws + OFF_BC, ws);
        spmm<<<384, 512, 0, stream>>>(adj, convs_b, l,
            (l < 2) ? stage_h(ws, l + 1) : nullptr, (l == 2) ? 1 : 0, ws);
    }
    tail<<<1, 768, 0, stream>>>(adj, fc_g, fc_b, lin_W, lin_b,
                                hid_g, hid_b, cls_W, cls_b, d_out, ws);
}